// Round 6
// baseline (619.587 us; speedup 1.0000x reference)
//
#include <hip/hip_runtime.h>
#include <hip/hip_bf16.h>

#define NV 512
#define NB 128
#define NCF 32    // fast-path column block
#define NC 64     // fallback column block

typedef float fv4 __attribute__((ext_vector_type(4)));
typedef float fv2 __attribute__((ext_vector_type(2)));
typedef float f32x4 __attribute__((ext_vector_type(4)));
typedef short bf8 __attribute__((ext_vector_type(8)));            // 8 bf16 (MFMA A/B frag)
typedef unsigned short u16x4 __attribute__((ext_vector_type(4)));
typedef unsigned short u16x8 __attribute__((ext_vector_type(8)));
typedef unsigned u32x2 __attribute__((ext_vector_type(2)));
typedef unsigned u32x4 __attribute__((ext_vector_type(4)));

// f32 -> bf16 RNE, scalar (off hot path)
__device__ __forceinline__ unsigned short f2bf(float f) {
  unsigned u = __builtin_bit_cast(unsigned, f);
  u += 0x7fffu + ((u >> 16) & 1u);
  return (unsigned short)(u >> 16);
}

// packed f32x2 -> bf16x2 (v_cvt_pk_bf16_f32); __hip_bfloat162 not trivially
// copyable -> memcpy, not bit_cast.
__device__ __forceinline__ unsigned cvt2(float lo, float hi) {
  __hip_bfloat162 h = __float22bfloat162_rn(make_float2(lo, hi));
  unsigned r;
  __builtin_memcpy(&r, &h, sizeof(r));
  return r;
}

__device__ __forceinline__ bf8 pack8(fv4 a0, fv4 a1) {
  u32x4 r;
  r[0] = cvt2(a0[0], a0[1]);
  r[1] = cvt2(a0[2], a0[3]);
  r[2] = cvt2(a1[0], a1[1]);
  r[3] = cvt2(a1[2], a1[3]);
  return __builtin_bit_cast(bf8, r);
}

// panel: [cols][512 rows] bf16, 1KB per col; XOR swizzle on 16B granules
__device__ __forceinline__ int swzL(int c, int r) {
  return ((c << 10) + (r << 1)) ^ ((c & 7) << 4);
}
// fallback staging layout
__device__ __forceinline__ int swzC(int j, int ii) {
  return ((j << 6) + (ii << 1)) ^ ((j & 3) << 4);
}

__device__ __forceinline__ void gload_lds16(const void* g, void* l) {
  __builtin_amdgcn_global_load_lds(
      (const __attribute__((address_space(1))) unsigned int*)g,
      (__attribute__((address_space(3))) unsigned int*)l, 16, 0, 0);
}

// ---------------------------------------------------------------------------
// Kernel 1: LT[b][j][i] = bf16(chol[b][i][j])   (64 MB bf16 workspace)
// ---------------------------------------------------------------------------
__global__ __launch_bounds__(256, 4)
void convert_LT_kernel(const float* __restrict__ chol, unsigned short* __restrict__ LT) {
  __shared__ unsigned short T[64][72];
  const int bid = blockIdx.x;
  const int b  = bid >> 6;
  const int t  = bid & 63;
  const int ti = t >> 3, tj = t & 7;

  const float* src = chol + ((size_t)b * NV + ti * 64) * NV + tj * 64;
  {
    const int r0 = threadIdx.x >> 4;
    const int c4 = (threadIdx.x & 15) * 4;
    #pragma unroll
    for (int p = 0; p < 4; ++p) {
      const int r = p * 16 + r0;
      fv4 v = *(const fv4*)(src + (size_t)r * NV + c4);
      T[c4 + 0][r] = f2bf(v[0]);
      T[c4 + 1][r] = f2bf(v[1]);
      T[c4 + 2][r] = f2bf(v[2]);
      T[c4 + 3][r] = f2bf(v[3]);
    }
  }
  __syncthreads();
  unsigned short* dst = LT + ((size_t)b * NV + tj * 64) * NV + ti * 64;
  const int c  = threadIdx.x >> 2;
  const int k8 = (threadIdx.x & 3) * 16;
  u16x8 o0, o1;
  #pragma unroll
  for (int q = 0; q < 8; ++q) { o0[q] = T[c][k8 + q]; o1[q] = T[c][k8 + 8 + q]; }
  *(u16x8*)(dst + (size_t)c * NV + k8)     = o0;
  *(u16x8*)(dst + (size_t)c * NV + k8 + 8) = o1;
}

// ---------------------------------------------------------------------------
// Kernel 2 (fast path): 64KB LDS, 512 threads, 2 blocks/CU
// wave tile 64 rows x 32 cols (acc[4][2])
// ---------------------------------------------------------------------------
__global__ __launch_bounds__(512, 4)
void fused_cholTE_fast(const float* __restrict__ covTE,
                       const float* __restrict__ chol,
                       const unsigned short* __restrict__ LT,
                       float* __restrict__ out) {
  __shared__ __align__(16) char lds[65536];
  char* sB0 = lds;          // A/B: cholC [c][r];  C/D: phi [c][j]   (32KB)
  char* sB1 = lds + 32768;  // T1 [c][i]                             (32KB)

  const int tid  = threadIdx.x;
  const int w    = tid >> 6;     // wave 0..7
  const int lane = tid & 63;
  const int lr   = lane & 15;
  const int lq   = lane >> 4;

  // 2048 WGs: XCD gets 16 batches x 16 c-blocks, batch-major within XCD
  const int bid = blockIdx.x;
  const int xcd = bid & 7;
  const int s   = bid >> 3;            // 0..255
  const int b   = xcd * 16 + (s >> 4); // batch
  const int c0  = (s & 15) * NCF;      // column block base

  const float*          Cb  = covTE + (size_t)b * NV * NV;
  const float*          Lb  = chol  + (size_t)b * NV * NV;
  const unsigned short* LTb = LT    + (size_t)b * NV * NV;
  float*                Ob  = out   + (size_t)b * NV * NV;

  // -------- Phase A: stage cholC (= LT rows c0..c0+31) -> sB0 via global_load_lds
  // wave w stages cols {w, w+8, w+16, w+24}; source granule pre-swizzled.
  #pragma unroll
  for (int cc = 0; cc < 4; ++cc) {
    const int c = cc * 8 + w;
    const unsigned short* src = LTb + (size_t)(c0 + c) * NV + ((lane ^ (c & 7)) * 8);
    gload_lds16(src, sB0 + c * 1024);
  }
  __syncthreads();

  f32x4 acc[4][2];

  // -------- Phase B: T1 = covTE @ cholC -> sB1 [c][i] bf16
  #pragma unroll
  for (int m = 0; m < 4; ++m)
    #pragma unroll
    for (int n = 0; n < 2; ++n) acc[m][n] = (f32x4)0.f;

  {
    const float* rowA[4];
    #pragma unroll
    for (int m = 0; m < 4; ++m)
      rowA[m] = Cb + (size_t)(w * 64 + m * 16 + lr) * NV + lq * 8;

    fv4 pa0[4], pa1[4];
    #pragma unroll
    for (int m = 0; m < 4; ++m) {
      pa0[m] = *(const fv4*)(rowA[m]);
      pa1[m] = *(const fv4*)(rowA[m] + 4);
    }

    for (int kb = 0; kb < 16; ++kb) {
      const int kbase = kb * 32 + lq * 8;
      bf8 bfr[2];
      #pragma unroll
      for (int n = 0; n < 2; ++n)
        bfr[n] = *(const bf8*)(sB0 + swzL(n * 16 + lr, kbase));
      fv4 na0[4], na1[4];
      if (kb < 15) {
        #pragma unroll
        for (int m = 0; m < 4; ++m) {
          na0[m] = *(const fv4*)(rowA[m] + (kb + 1) * 32);
          na1[m] = *(const fv4*)(rowA[m] + (kb + 1) * 32 + 4);
        }
      }
      #pragma unroll
      for (int m = 0; m < 4; ++m) {
        bf8 af = pack8(pa0[m], pa1[m]);
        #pragma unroll
        for (int n = 0; n < 2; ++n)
          acc[m][n] = __builtin_amdgcn_mfma_f32_16x16x32_bf16(af, bfr[n], acc[m][n], 0, 0, 0);
      }
      if (kb < 15) {
        #pragma unroll
        for (int m = 0; m < 4; ++m) { pa0[m] = na0[m]; pa1[m] = na1[m]; }
      }
    }
  }
  #pragma unroll
  for (int m = 0; m < 4; ++m) {
    #pragma unroll
    for (int n = 0; n < 2; ++n) {
      f32x4 a = acc[m][n];
      u32x2 pk; pk[0] = cvt2(a[0], a[1]); pk[1] = cvt2(a[2], a[3]);
      *(u32x2*)(sB1 + swzL(n * 16 + lr, w * 64 + m * 16 + lq * 4)) = pk;
    }
  }
  __syncthreads();

  // -------- Phase C: phi = cholT @ T1 (masked) -> sB0 [c][j] bf16
  #pragma unroll
  for (int m = 0; m < 4; ++m)
    #pragma unroll
    for (int n = 0; n < 2; ++n) acc[m][n] = (f32x4)0.f;

  {
    const unsigned short* rowL[4];
    #pragma unroll
    for (int jt = 0; jt < 4; ++jt)
      rowL[jt] = LTb + (size_t)(w * 64 + jt * 16 + lr) * NV + lq * 8;

    bf8 pl[4];
    #pragma unroll
    for (int jt = 0; jt < 4; ++jt) pl[jt] = *(const bf8*)(rowL[jt]);

    for (int ib = 0; ib < 16; ++ib) {
      const int kbase = ib * 32 + lq * 8;
      bf8 bt[2];
      #pragma unroll
      for (int n = 0; n < 2; ++n)
        bt[n] = *(const bf8*)(sB1 + swzL(n * 16 + lr, kbase));
      bf8 nl[4];
      if (ib < 15) {
        #pragma unroll
        for (int jt = 0; jt < 4; ++jt)
          nl[jt] = *(const bf8*)(rowL[jt] + (ib + 1) * 32);
      }
      #pragma unroll
      for (int jt = 0; jt < 4; ++jt)
        #pragma unroll
        for (int n = 0; n < 2; ++n)
          acc[jt][n] = __builtin_amdgcn_mfma_f32_16x16x32_bf16(pl[jt], bt[n], acc[jt][n], 0, 0, 0);
      if (ib < 15) {
        #pragma unroll
        for (int jt = 0; jt < 4; ++jt) pl[jt] = nl[jt];
      }
    }
  }
  // mask (strict lower=1, diag=0.5, upper=0) -> sB0 [c][j]
  #pragma unroll
  for (int jt = 0; jt < 4; ++jt) {
    #pragma unroll
    for (int n = 0; n < 2; ++n) {
      f32x4 a = acc[jt][n];
      const int gk = c0 + n * 16 + lr;
      const int j0 = w * 64 + jt * 16 + lq * 4;
      float f[4];
      #pragma unroll
      for (int q = 0; q < 4; ++q) {
        const int j = j0 + q;
        f[q] = (j > gk) ? a[q] : ((j == gk) ? 0.5f * a[q] : 0.f);
      }
      u32x2 pk; pk[0] = cvt2(f[0], f[1]); pk[1] = cvt2(f[2], f[3]);
      *(u32x2*)(sB0 + swzL(n * 16 + lr, j0)) = pk;
    }
  }
  __syncthreads();

  // -------- Phase D: out = -chol @ phi
  #pragma unroll
  for (int m = 0; m < 4; ++m)
    #pragma unroll
    for (int n = 0; n < 2; ++n) acc[m][n] = (f32x4)0.f;

  {
    const float* rowA[4];
    #pragma unroll
    for (int m = 0; m < 4; ++m)
      rowA[m] = Lb + (size_t)(w * 64 + m * 16 + lr) * NV + lq * 8;

    fv4 pa0[4], pa1[4];
    #pragma unroll
    for (int m = 0; m < 4; ++m) {
      pa0[m] = *(const fv4*)(rowA[m]);
      pa1[m] = *(const fv4*)(rowA[m] + 4);
    }

    for (int kb = 0; kb < 16; ++kb) {
      const int kbase = kb * 32 + lq * 8;
      bf8 bp[2];
      #pragma unroll
      for (int n = 0; n < 2; ++n)
        bp[n] = *(const bf8*)(sB0 + swzL(n * 16 + lr, kbase));
      fv4 na0[4], na1[4];
      if (kb < 15) {
        #pragma unroll
        for (int m = 0; m < 4; ++m) {
          na0[m] = *(const fv4*)(rowA[m] + (kb + 1) * 32);
          na1[m] = *(const fv4*)(rowA[m] + (kb + 1) * 32 + 4);
        }
      }
      #pragma unroll
      for (int m = 0; m < 4; ++m) {
        bf8 af = pack8(pa0[m], pa1[m]);
        #pragma unroll
        for (int n = 0; n < 2; ++n)
          acc[m][n] = __builtin_amdgcn_mfma_f32_16x16x32_bf16(af, bp[n], acc[m][n], 0, 0, 0);
      }
      if (kb < 15) {
        #pragma unroll
        for (int m = 0; m < 4; ++m) { pa0[m] = na0[m]; pa1[m] = na1[m]; }
      }
    }
  }
  #pragma unroll
  for (int m = 0; m < 4; ++m) {
    const int i0 = w * 64 + m * 16 + lq * 4;
    #pragma unroll
    for (int n = 0; n < 2; ++n) {
      f32x4 a = acc[m][n];
      const int col = c0 + n * 16 + lr;
      #pragma unroll
      for (int q = 0; q < 4; ++q)
        Ob[(size_t)(i0 + q) * NV + col] = -a[q];
    }
  }
}

// ---------------------------------------------------------------------------
// Fallback (R1-style, NC=64) for ws_size < 64 MB
// ---------------------------------------------------------------------------
__global__ __launch_bounds__(1024, 1)
void fused_cholTE_fallback(const float* __restrict__ covTE,
                           const float* __restrict__ chol,
                           float* __restrict__ out) {
  __shared__ __align__(16) char lds[131072];
  char* sB0 = lds;
  char* sB1 = lds + 65536;
  char* sCh = lds;

  const int tid  = threadIdx.x;
  const int w    = tid >> 6;
  const int lane = tid & 63;
  const int lr   = lane & 15;
  const int lq   = lane >> 4;

  const int bid = blockIdx.x;
  const int xcd = bid & 7;
  const int s   = bid >> 3;
  const int b   = xcd * 16 + (s >> 3);
  const int c0  = (s & 7) * NC;

  const float* Cb = covTE + (size_t)b * NV * NV;
  const float* Lb = chol  + (size_t)b * NV * NV;
  float*       Ob = out   + (size_t)b * NV * NV;

  {
    const int rr = tid >> 4;
    const int cc = (tid & 15) * 4;
    #pragma unroll
    for (int p = 0; p < 8; ++p) {
      const int r = p * 64 + rr;
      fv4 v = *(const fv4*)(Lb + (size_t)r * NV + c0 + cc);
      *(unsigned short*)(sB0 + swzL(cc + 0, r)) = f2bf(v[0]);
      *(unsigned short*)(sB0 + swzL(cc + 1, r)) = f2bf(v[1]);
      *(unsigned short*)(sB0 + swzL(cc + 2, r)) = f2bf(v[2]);
      *(unsigned short*)(sB0 + swzL(cc + 3, r)) = f2bf(v[3]);
    }
  }
  __syncthreads();

  f32x4 acc[2][4];
  #pragma unroll
  for (int m = 0; m < 2; ++m)
    #pragma unroll
    for (int n = 0; n < 4; ++n) acc[m][n] = (f32x4)0.f;

  for (int kb = 0; kb < 16; ++kb) {
    const int kbase = kb * 32 + lq * 8;
    bf8 bfr[4];
    #pragma unroll
    for (int n = 0; n < 4; ++n)
      bfr[n] = *(const bf8*)(sB0 + swzL(n * 16 + lr, kbase));
    #pragma unroll
    for (int m = 0; m < 2; ++m) {
      const float* p = Cb + (size_t)(w * 32 + m * 16 + lr) * NV + kbase;
      fv4 a0 = *(const fv4*)p;
      fv4 a1 = *(const fv4*)(p + 4);
      bf8 af = pack8(a0, a1);
      #pragma unroll
      for (int n = 0; n < 4; ++n)
        acc[m][n] = __builtin_amdgcn_mfma_f32_16x16x32_bf16(af, bfr[n], acc[m][n], 0, 0, 0);
    }
  }
  #pragma unroll
  for (int m = 0; m < 2; ++m) {
    #pragma unroll
    for (int n = 0; n < 4; ++n) {
      f32x4 a = acc[m][n];
      u32x2 pk; pk[0] = cvt2(a[0], a[1]); pk[1] = cvt2(a[2], a[3]);
      *(u32x2*)(sB1 + swzL(n * 16 + lr, w * 32 + m * 16 + lq * 4)) = pk;
    }
  }
  __syncthreads();

  #pragma unroll
  for (int m = 0; m < 2; ++m)
    #pragma unroll
    for (int n = 0; n < 4; ++n) acc[m][n] = (f32x4)0.f;

  const int sj = (tid & 255) * 2;
  const int so = tid >> 8;

  fv2 raw[8];
  {
    const float* src = Lb + (size_t)(so * 8) * NV + sj;
    #pragma unroll
    for (int r = 0; r < 8; ++r) raw[r] = *(const fv2*)(src + (size_t)r * NV);
    u16x8 p0, p1;
    #pragma unroll
    for (int r = 0; r < 8; ++r) { p0[r] = f2bf(raw[r][0]); p1[r] = f2bf(raw[r][1]); }
    *(u16x8*)(sCh + swzC(sj + 0, so * 8)) = p0;
    *(u16x8*)(sCh + swzC(sj + 1, so * 8)) = p1;
  }
  __syncthreads();

  for (int ib = 0; ib < 16; ++ib) {
    if (ib + 1 < 16) {
      const float* src = Lb + (size_t)((ib + 1) * 32 + so * 8) * NV + sj;
      #pragma unroll
      for (int r = 0; r < 8; ++r) raw[r] = *(const fv2*)(src + (size_t)r * NV);
    }
    bf8 bt[4];
    #pragma unroll
    for (int n = 0; n < 4; ++n)
      bt[n] = *(const bf8*)(sB1 + swzL(n * 16 + lr, ib * 32 + lq * 8));
    #pragma unroll
    for (int jt = 0; jt < 2; ++jt) {
      bf8 af = *(const bf8*)(sCh + swzC(w * 32 + jt * 16 + lr, lq * 8));
      #pragma unroll
      for (int n = 0; n < 4; ++n)
        acc[jt][n] = __builtin_amdgcn_mfma_f32_16x16x32_bf16(af, bt[n], acc[jt][n], 0, 0, 0);
    }
    __syncthreads();
    if (ib + 1 < 16) {
      u16x8 p0, p1;
      #pragma unroll
      for (int r = 0; r < 8; ++r) { p0[r] = f2bf(raw[r][0]); p1[r] = f2bf(raw[r][1]); }
      *(u16x8*)(sCh + swzC(sj + 0, so * 8)) = p0;
      *(u16x8*)(sCh + swzC(sj + 1, so * 8)) = p1;
    }
    __syncthreads();
  }

  #pragma unroll
  for (int jt = 0; jt < 2; ++jt) {
    #pragma unroll
    for (int n = 0; n < 4; ++n) {
      f32x4 a = acc[jt][n];
      const int gk = c0 + n * 16 + lr;
      const int j0 = w * 32 + jt * 16 + lq * 4;
      float f[4];
      #pragma unroll
      for (int q = 0; q < 4; ++q) {
        const int j = j0 + q;
        f[q] = (j > gk) ? a[q] : ((j == gk) ? 0.5f * a[q] : 0.f);
      }
      u32x2 pk; pk[0] = cvt2(f[0], f[1]); pk[1] = cvt2(f[2], f[3]);
      *(u32x2*)(sB0 + swzL(n * 16 + lr, j0)) = pk;
    }
  }
  __syncthreads();

  #pragma unroll
  for (int m = 0; m < 2; ++m)
    #pragma unroll
    for (int n = 0; n < 4; ++n) acc[m][n] = (f32x4)0.f;

  for (int kb = 0; kb < 16; ++kb) {
    const int kbase = kb * 32 + lq * 8;
    bf8 bp[4];
    #pragma unroll
    for (int n = 0; n < 4; ++n)
      bp[n] = *(const bf8*)(sB0 + swzL(n * 16 + lr, kbase));
    #pragma unroll
    for (int m = 0; m < 2; ++m) {
      const float* p = Lb + (size_t)(w * 32 + m * 16 + lr) * NV + kbase;
      fv4 a0 = *(const fv4*)p;
      fv4 a1 = *(const fv4*)(p + 4);
      bf8 af = pack8(a0, a1);
      #pragma unroll
      for (int n = 0; n < 4; ++n)
        acc[m][n] = __builtin_amdgcn_mfma_f32_16x16x32_bf16(af, bp[n], acc[m][n], 0, 0, 0);
    }
  }
  #pragma unroll
  for (int m = 0; m < 2; ++m) {
    const int i0 = w * 32 + m * 16 + lq * 4;
    #pragma unroll
    for (int n = 0; n < 4; ++n) {
      f32x4 a = acc[m][n];
      const int col = c0 + n * 16 + lr;
      #pragma unroll
      for (int q = 0; q < 4; ++q)
        Ob[(size_t)(i0 + q) * NV + col] = -a[q];
    }
  }
}

extern "C" void kernel_launch(void* const* d_in, const int* in_sizes, int n_in,
                              void* d_out, int out_size, void* d_ws, size_t ws_size,
                              hipStream_t stream) {
  const float* muTE  = (const float*)d_in[0];
  const float* covTE = (const float*)d_in[1];
  const float* chol  = (const float*)d_in[2];
  float* out = (float*)d_out;

  (void)hipMemcpyAsync(out, muTE, (size_t)NB * NV * sizeof(float),
                       hipMemcpyDeviceToDevice, stream);

  float* cholTE = out + (size_t)NB * NV;
  const size_t lt_bytes = (size_t)NB * NV * NV * sizeof(unsigned short); // 64 MB

  if (ws_size >= lt_bytes) {
    unsigned short* LT = (unsigned short*)d_ws;
    convert_LT_kernel<<<dim3(NB * 64), dim3(256), 0, stream>>>(chol, LT);
    fused_cholTE_fast<<<dim3(NB * (NV / NCF)), dim3(512), 0, stream>>>(
        covTE, chol, LT, cholTE);
  } else {
    fused_cholTE_fallback<<<dim3(NB * (NV / NC)), dim3(1024), 0, stream>>>(
        covTE, chol, cholTE);
  }
}

// Round 7
// 480.203 us; speedup vs baseline: 1.2903x; 1.2903x over previous
//
#include <hip/hip_runtime.h>
#include <hip/hip_bf16.h>

#define NV 512
#define NB 128
#define NC 64

typedef float fv4 __attribute__((ext_vector_type(4)));
typedef float fv2 __attribute__((ext_vector_type(2)));
typedef float f32x4 __attribute__((ext_vector_type(4)));
typedef short bf8 __attribute__((ext_vector_type(8)));            // 8 bf16 (MFMA A/B frag)
typedef unsigned short u16x4 __attribute__((ext_vector_type(4)));
typedef unsigned short u16x8 __attribute__((ext_vector_type(8)));
typedef unsigned u32x2 __attribute__((ext_vector_type(2)));
typedef unsigned u32x4 __attribute__((ext_vector_type(4)));

// f32 -> bf16 RNE, scalar (off hot path)
__device__ __forceinline__ unsigned short f2bf(float f) {
  unsigned u = __builtin_bit_cast(unsigned, f);
  u += 0x7fffu + ((u >> 16) & 1u);
  return (unsigned short)(u >> 16);
}

// packed f32x2 -> bf16x2 (v_cvt_pk_bf16_f32); __hip_bfloat162 not trivially
// copyable -> memcpy, not bit_cast.
__device__ __forceinline__ unsigned cvt2(float lo, float hi) {
  __hip_bfloat162 h = __float22bfloat162_rn(make_float2(lo, hi));
  unsigned r;
  __builtin_memcpy(&r, &h, sizeof(r));
  return r;
}

__device__ __forceinline__ bf8 pack8(fv4 a0, fv4 a1) {
  u32x4 r;
  r[0] = cvt2(a0[0], a0[1]);
  r[1] = cvt2(a0[2], a0[3]);
  r[2] = cvt2(a1[0], a1[1]);
  r[3] = cvt2(a1[2], a1[3]);
  return __builtin_bit_cast(bf8, r);
}

// panel: [cols][512 rows] bf16, 1KB per col; XOR swizzle on 16B granules
__device__ __forceinline__ int swzL(int c, int r) {
  return ((c << 10) + (r << 1)) ^ ((c & 7) << 4);
}
// fallback staging layout
__device__ __forceinline__ int swzC(int j, int ii) {
  return ((j << 6) + (ii << 1)) ^ ((j & 3) << 4);
}

__device__ __forceinline__ void gload_lds16(const void* g, void* l) {
  __builtin_amdgcn_global_load_lds(
      (const __attribute__((address_space(1))) unsigned int*)g,
      (__attribute__((address_space(3))) unsigned int*)l, 16, 0, 0);
}

// ---------------------------------------------------------------------------
// Kernel 1: LT[b][j][i] = bf16(chol[b][i][j])   (64 MB bf16 workspace)
// ---------------------------------------------------------------------------
__global__ __launch_bounds__(256, 4)
void convert_LT_kernel(const float* __restrict__ chol, unsigned short* __restrict__ LT) {
  __shared__ unsigned short T[64][72];
  const int bid = blockIdx.x;
  const int b  = bid >> 6;
  const int t  = bid & 63;
  const int ti = t >> 3, tj = t & 7;

  const float* src = chol + ((size_t)b * NV + ti * 64) * NV + tj * 64;
  {
    const int r0 = threadIdx.x >> 4;
    const int c4 = (threadIdx.x & 15) * 4;
    #pragma unroll
    for (int p = 0; p < 4; ++p) {
      const int r = p * 16 + r0;
      fv4 v = *(const fv4*)(src + (size_t)r * NV + c4);
      T[c4 + 0][r] = f2bf(v[0]);
      T[c4 + 1][r] = f2bf(v[1]);
      T[c4 + 2][r] = f2bf(v[2]);
      T[c4 + 3][r] = f2bf(v[3]);
    }
  }
  __syncthreads();
  unsigned short* dst = LT + ((size_t)b * NV + tj * 64) * NV + ti * 64;
  const int c  = threadIdx.x >> 2;
  const int k8 = (threadIdx.x & 3) * 16;
  u16x8 o0, o1;
  #pragma unroll
  for (int q = 0; q < 8; ++q) { o0[q] = T[c][k8 + q]; o1[q] = T[c][k8 + 8 + q]; }
  *(u16x8*)(dst + (size_t)c * NV + k8)     = o0;
  *(u16x8*)(dst + (size_t)c * NV + k8 + 8) = o1;
}

// ---------------------------------------------------------------------------
// Kernel 2 (fast path): R4 geometry (NC=64, 1024 thr, 128KB LDS) +
// depth-2 pinned register pipeline in all three K-loops.
// ---------------------------------------------------------------------------
__global__ __launch_bounds__(1024, 1)
void fused_cholTE_fast(const float* __restrict__ covTE,
                       const float* __restrict__ chol,
                       const unsigned short* __restrict__ LT,
                       float* __restrict__ out) {
  __shared__ __align__(16) char lds[131072];
  char* sB0 = lds;          // A/B: cholC [c][r];  C/D: phi [c][j]
  char* sB1 = lds + 65536;  // T1 [c][i]

  const int tid  = threadIdx.x;
  const int w    = tid >> 6;
  const int lane = tid & 63;
  const int lr   = lane & 15;
  const int lq   = lane >> 4;

  const int bid = blockIdx.x;
  const int xcd = bid & 7;
  const int s   = bid >> 3;
  const int b   = xcd * 16 + (s >> 3);
  const int c0  = (s & 7) * NC;

  const float*          Cb  = covTE + (size_t)b * NV * NV;
  const float*          Lb  = chol  + (size_t)b * NV * NV;
  const unsigned short* LTb = LT    + (size_t)b * NV * NV;
  float*                Ob  = out   + (size_t)b * NV * NV;

  // -------- Phase A: stage cholC (= LT rows c0..c0+63) -> sB0 via global_load_lds
  #pragma unroll
  for (int cc = 0; cc < 4; ++cc) {
    const int c = cc * 16 + w;
    const unsigned short* src = LTb + (size_t)(c0 + c) * NV + ((lane ^ (c & 7)) * 8);
    gload_lds16(src, sB0 + c * 1024);
  }
  __syncthreads();

  f32x4 acc[2][4];

  // -------- Phase B: T1 = covTE @ cholC -> sB1 [c][i] bf16
  #pragma unroll
  for (int m = 0; m < 2; ++m)
    #pragma unroll
    for (int n = 0; n < 4; ++n) acc[m][n] = (f32x4)0.f;

  {
    const float* rowA[2];
    #pragma unroll
    for (int m = 0; m < 2; ++m)
      rowA[m] = Cb + (size_t)(w * 32 + m * 16 + lr) * NV + lq * 8;

    // depth-2 pipeline, static X/Y buffers
    fv4 Xa0[2], Xa1[2], Ya0[2], Ya1[2];
    #pragma unroll
    for (int m = 0; m < 2; ++m) {
      Xa0[m] = *(const fv4*)(rowA[m]);          Xa1[m] = *(const fv4*)(rowA[m] + 4);
      Ya0[m] = *(const fv4*)(rowA[m] + 32);     Ya1[m] = *(const fv4*)(rowA[m] + 36);
    }

    #pragma unroll
    for (int kb = 0; kb < 16; kb += 2) {
      // even half: consume X(kb), issue X <- kb+2
      {
        const int kbase = kb * 32 + lq * 8;
        bf8 bfr[4];
        #pragma unroll
        for (int n = 0; n < 4; ++n)
          bfr[n] = *(const bf8*)(sB0 + swzL(n * 16 + lr, kbase));
        bf8 af[2];
        #pragma unroll
        for (int m = 0; m < 2; ++m) af[m] = pack8(Xa0[m], Xa1[m]);
        if (kb + 2 < 16) {
          #pragma unroll
          for (int m = 0; m < 2; ++m) {
            Xa0[m] = *(const fv4*)(rowA[m] + (kb + 2) * 32);
            Xa1[m] = *(const fv4*)(rowA[m] + (kb + 2) * 32 + 4);
          }
        }
        __builtin_amdgcn_sched_barrier(0);   // keep prefetch issue above MFMAs
        #pragma unroll
        for (int m = 0; m < 2; ++m)
          #pragma unroll
          for (int n = 0; n < 4; ++n)
            acc[m][n] = __builtin_amdgcn_mfma_f32_16x16x32_bf16(af[m], bfr[n], acc[m][n], 0, 0, 0);
      }
      // odd half: consume Y(kb+1), issue Y <- kb+3
      {
        const int kbase = (kb + 1) * 32 + lq * 8;
        bf8 bfr[4];
        #pragma unroll
        for (int n = 0; n < 4; ++n)
          bfr[n] = *(const bf8*)(sB0 + swzL(n * 16 + lr, kbase));
        bf8 af[2];
        #pragma unroll
        for (int m = 0; m < 2; ++m) af[m] = pack8(Ya0[m], Ya1[m]);
        if (kb + 3 < 16) {
          #pragma unroll
          for (int m = 0; m < 2; ++m) {
            Ya0[m] = *(const fv4*)(rowA[m] + (kb + 3) * 32);
            Ya1[m] = *(const fv4*)(rowA[m] + (kb + 3) * 32 + 4);
          }
        }
        __builtin_amdgcn_sched_barrier(0);
        #pragma unroll
        for (int m = 0; m < 2; ++m)
          #pragma unroll
          for (int n = 0; n < 4; ++n)
            acc[m][n] = __builtin_amdgcn_mfma_f32_16x16x32_bf16(af[m], bfr[n], acc[m][n], 0, 0, 0);
      }
    }
  }
  #pragma unroll
  for (int m = 0; m < 2; ++m) {
    #pragma unroll
    for (int n = 0; n < 4; ++n) {
      f32x4 a = acc[m][n];
      u32x2 pk; pk[0] = cvt2(a[0], a[1]); pk[1] = cvt2(a[2], a[3]);
      *(u32x2*)(sB1 + swzL(n * 16 + lr, w * 32 + m * 16 + lq * 4)) = pk;
    }
  }
  __syncthreads();

  // -------- Phase C: phi = cholT @ T1 (masked) -> sB0 [c][j] bf16
  #pragma unroll
  for (int m = 0; m < 2; ++m)
    #pragma unroll
    for (int n = 0; n < 4; ++n) acc[m][n] = (f32x4)0.f;

  {
    const unsigned short* rowL[2];
    #pragma unroll
    for (int jt = 0; jt < 2; ++jt)
      rowL[jt] = LTb + (size_t)(w * 32 + jt * 16 + lr) * NV + lq * 8;

    bf8 Xl[2], Yl[2];
    #pragma unroll
    for (int jt = 0; jt < 2; ++jt) {
      Xl[jt] = *(const bf8*)(rowL[jt]);
      Yl[jt] = *(const bf8*)(rowL[jt] + 32);
    }

    #pragma unroll
    for (int ib = 0; ib < 16; ib += 2) {
      // even half
      {
        const int kbase = ib * 32 + lq * 8;
        bf8 bt[4];
        #pragma unroll
        for (int n = 0; n < 4; ++n)
          bt[n] = *(const bf8*)(sB1 + swzL(n * 16 + lr, kbase));
        bf8 af[2];
        #pragma unroll
        for (int jt = 0; jt < 2; ++jt) af[jt] = Xl[jt];
        if (ib + 2 < 16) {
          #pragma unroll
          for (int jt = 0; jt < 2; ++jt)
            Xl[jt] = *(const bf8*)(rowL[jt] + (ib + 2) * 32);
        }
        __builtin_amdgcn_sched_barrier(0);
        #pragma unroll
        for (int jt = 0; jt < 2; ++jt)
          #pragma unroll
          for (int n = 0; n < 4; ++n)
            acc[jt][n] = __builtin_amdgcn_mfma_f32_16x16x32_bf16(af[jt], bt[n], acc[jt][n], 0, 0, 0);
      }
      // odd half
      {
        const int kbase = (ib + 1) * 32 + lq * 8;
        bf8 bt[4];
        #pragma unroll
        for (int n = 0; n < 4; ++n)
          bt[n] = *(const bf8*)(sB1 + swzL(n * 16 + lr, kbase));
        bf8 af[2];
        #pragma unroll
        for (int jt = 0; jt < 2; ++jt) af[jt] = Yl[jt];
        if (ib + 3 < 16) {
          #pragma unroll
          for (int jt = 0; jt < 2; ++jt)
            Yl[jt] = *(const bf8*)(rowL[jt] + (ib + 3) * 32);
        }
        __builtin_amdgcn_sched_barrier(0);
        #pragma unroll
        for (int jt = 0; jt < 2; ++jt)
          #pragma unroll
          for (int n = 0; n < 4; ++n)
            acc[jt][n] = __builtin_amdgcn_mfma_f32_16x16x32_bf16(af[jt], bt[n], acc[jt][n], 0, 0, 0);
      }
    }
  }
  // mask (strict lower=1, diag=0.5, upper=0) -> sB0 [c][j]
  #pragma unroll
  for (int jt = 0; jt < 2; ++jt) {
    #pragma unroll
    for (int n = 0; n < 4; ++n) {
      f32x4 a = acc[jt][n];
      const int gk = c0 + n * 16 + lr;
      const int j0 = w * 32 + jt * 16 + lq * 4;
      float f[4];
      #pragma unroll
      for (int q = 0; q < 4; ++q) {
        const int j = j0 + q;
        f[q] = (j > gk) ? a[q] : ((j == gk) ? 0.5f * a[q] : 0.f);
      }
      u32x2 pk; pk[0] = cvt2(f[0], f[1]); pk[1] = cvt2(f[2], f[3]);
      *(u32x2*)(sB0 + swzL(n * 16 + lr, j0)) = pk;
    }
  }
  __syncthreads();

  // -------- Phase D: out = -chol @ phi
  #pragma unroll
  for (int m = 0; m < 2; ++m)
    #pragma unroll
    for (int n = 0; n < 4; ++n) acc[m][n] = (f32x4)0.f;

  {
    const float* rowA[2];
    #pragma unroll
    for (int m = 0; m < 2; ++m)
      rowA[m] = Lb + (size_t)(w * 32 + m * 16 + lr) * NV + lq * 8;

    fv4 Xa0[2], Xa1[2], Ya0[2], Ya1[2];
    #pragma unroll
    for (int m = 0; m < 2; ++m) {
      Xa0[m] = *(const fv4*)(rowA[m]);          Xa1[m] = *(const fv4*)(rowA[m] + 4);
      Ya0[m] = *(const fv4*)(rowA[m] + 32);     Ya1[m] = *(const fv4*)(rowA[m] + 36);
    }

    #pragma unroll
    for (int kb = 0; kb < 16; kb += 2) {
      {
        const int kbase = kb * 32 + lq * 8;
        bf8 bp[4];
        #pragma unroll
        for (int n = 0; n < 4; ++n)
          bp[n] = *(const bf8*)(sB0 + swzL(n * 16 + lr, kbase));
        bf8 af[2];
        #pragma unroll
        for (int m = 0; m < 2; ++m) af[m] = pack8(Xa0[m], Xa1[m]);
        if (kb + 2 < 16) {
          #pragma unroll
          for (int m = 0; m < 2; ++m) {
            Xa0[m] = *(const fv4*)(rowA[m] + (kb + 2) * 32);
            Xa1[m] = *(const fv4*)(rowA[m] + (kb + 2) * 32 + 4);
          }
        }
        __builtin_amdgcn_sched_barrier(0);
        #pragma unroll
        for (int m = 0; m < 2; ++m)
          #pragma unroll
          for (int n = 0; n < 4; ++n)
            acc[m][n] = __builtin_amdgcn_mfma_f32_16x16x32_bf16(af[m], bp[n], acc[m][n], 0, 0, 0);
      }
      {
        const int kbase = (kb + 1) * 32 + lq * 8;
        bf8 bp[4];
        #pragma unroll
        for (int n = 0; n < 4; ++n)
          bp[n] = *(const bf8*)(sB0 + swzL(n * 16 + lr, kbase));
        bf8 af[2];
        #pragma unroll
        for (int m = 0; m < 2; ++m) af[m] = pack8(Ya0[m], Ya1[m]);
        if (kb + 3 < 16) {
          #pragma unroll
          for (int m = 0; m < 2; ++m) {
            Ya0[m] = *(const fv4*)(rowA[m] + (kb + 3) * 32);
            Ya1[m] = *(const fv4*)(rowA[m] + (kb + 3) * 32 + 4);
          }
        }
        __builtin_amdgcn_sched_barrier(0);
        #pragma unroll
        for (int m = 0; m < 2; ++m)
          #pragma unroll
          for (int n = 0; n < 4; ++n)
            acc[m][n] = __builtin_amdgcn_mfma_f32_16x16x32_bf16(af[m], bp[n], acc[m][n], 0, 0, 0);
      }
    }
  }
  #pragma unroll
  for (int m = 0; m < 2; ++m) {
    const int i0 = w * 32 + m * 16 + lq * 4;
    #pragma unroll
    for (int n = 0; n < 4; ++n) {
      f32x4 a = acc[m][n];
      const int col = c0 + n * 16 + lr;
      #pragma unroll
      for (int q = 0; q < 4; ++q)
        Ob[(size_t)(i0 + q) * NV + col] = -a[q];
    }
  }
}

// ---------------------------------------------------------------------------
// Fallback (R1-style, NC=64) for ws_size < 64 MB
// ---------------------------------------------------------------------------
__global__ __launch_bounds__(1024, 1)
void fused_cholTE_fallback(const float* __restrict__ covTE,
                           const float* __restrict__ chol,
                           float* __restrict__ out) {
  __shared__ __align__(16) char lds[131072];
  char* sB0 = lds;
  char* sB1 = lds + 65536;
  char* sCh = lds;

  const int tid  = threadIdx.x;
  const int w    = tid >> 6;
  const int lane = tid & 63;
  const int lr   = lane & 15;
  const int lq   = lane >> 4;

  const int bid = blockIdx.x;
  const int xcd = bid & 7;
  const int s   = bid >> 3;
  const int b   = xcd * 16 + (s >> 3);
  const int c0  = (s & 7) * NC;

  const float* Cb = covTE + (size_t)b * NV * NV;
  const float* Lb = chol  + (size_t)b * NV * NV;
  float*       Ob = out   + (size_t)b * NV * NV;

  {
    const int rr = tid >> 4;
    const int cc = (tid & 15) * 4;
    #pragma unroll
    for (int p = 0; p < 8; ++p) {
      const int r = p * 64 + rr;
      fv4 v = *(const fv4*)(Lb + (size_t)r * NV + c0 + cc);
      *(unsigned short*)(sB0 + swzL(cc + 0, r)) = f2bf(v[0]);
      *(unsigned short*)(sB0 + swzL(cc + 1, r)) = f2bf(v[1]);
      *(unsigned short*)(sB0 + swzL(cc + 2, r)) = f2bf(v[2]);
      *(unsigned short*)(sB0 + swzL(cc + 3, r)) = f2bf(v[3]);
    }
  }
  __syncthreads();

  f32x4 acc[2][4];
  #pragma unroll
  for (int m = 0; m < 2; ++m)
    #pragma unroll
    for (int n = 0; n < 4; ++n) acc[m][n] = (f32x4)0.f;

  for (int kb = 0; kb < 16; ++kb) {
    const int kbase = kb * 32 + lq * 8;
    bf8 bfr[4];
    #pragma unroll
    for (int n = 0; n < 4; ++n)
      bfr[n] = *(const bf8*)(sB0 + swzL(n * 16 + lr, kbase));
    #pragma unroll
    for (int m = 0; m < 2; ++m) {
      const float* p = Cb + (size_t)(w * 32 + m * 16 + lr) * NV + kbase;
      fv4 a0 = *(const fv4*)p;
      fv4 a1 = *(const fv4*)(p + 4);
      bf8 af = pack8(a0, a1);
      #pragma unroll
      for (int n = 0; n < 4; ++n)
        acc[m][n] = __builtin_amdgcn_mfma_f32_16x16x32_bf16(af, bfr[n], acc[m][n], 0, 0, 0);
    }
  }
  #pragma unroll
  for (int m = 0; m < 2; ++m) {
    #pragma unroll
    for (int n = 0; n < 4; ++n) {
      f32x4 a = acc[m][n];
      u32x2 pk; pk[0] = cvt2(a[0], a[1]); pk[1] = cvt2(a[2], a[3]);
      *(u32x2*)(sB1 + swzL(n * 16 + lr, w * 32 + m * 16 + lq * 4)) = pk;
    }
  }
  __syncthreads();

  #pragma unroll
  for (int m = 0; m < 2; ++m)
    #pragma unroll
    for (int n = 0; n < 4; ++n) acc[m][n] = (f32x4)0.f;

  const int sj = (tid & 255) * 2;
  const int so = tid >> 8;

  fv2 raw[8];
  {
    const float* src = Lb + (size_t)(so * 8) * NV + sj;
    #pragma unroll
    for (int r = 0; r < 8; ++r) raw[r] = *(const fv2*)(src + (size_t)r * NV);
    u16x8 p0, p1;
    #pragma unroll
    for (int r = 0; r < 8; ++r) { p0[r] = f2bf(raw[r][0]); p1[r] = f2bf(raw[r][1]); }
    *(u16x8*)(sCh + swzC(sj + 0, so * 8)) = p0;
    *(u16x8*)(sCh + swzC(sj + 1, so * 8)) = p1;
  }
  __syncthreads();

  for (int ib = 0; ib < 16; ++ib) {
    if (ib + 1 < 16) {
      const float* src = Lb + (size_t)((ib + 1) * 32 + so * 8) * NV + sj;
      #pragma unroll
      for (int r = 0; r < 8; ++r) raw[r] = *(const fv2*)(src + (size_t)r * NV);
    }
    bf8 bt[4];
    #pragma unroll
    for (int n = 0; n < 4; ++n)
      bt[n] = *(const bf8*)(sB1 + swzL(n * 16 + lr, ib * 32 + lq * 8));
    #pragma unroll
    for (int jt = 0; jt < 2; ++jt) {
      bf8 af = *(const bf8*)(sCh + swzC(w * 32 + jt * 16 + lr, lq * 8));
      #pragma unroll
      for (int n = 0; n < 4; ++n)
        acc[jt][n] = __builtin_amdgcn_mfma_f32_16x16x32_bf16(af, bt[n], acc[jt][n], 0, 0, 0);
    }
    __syncthreads();
    if (ib + 1 < 16) {
      u16x8 p0, p1;
      #pragma unroll
      for (int r = 0; r < 8; ++r) { p0[r] = f2bf(raw[r][0]); p1[r] = f2bf(raw[r][1]); }
      *(u16x8*)(sCh + swzC(sj + 0, so * 8)) = p0;
      *(u16x8*)(sCh + swzC(sj + 1, so * 8)) = p1;
    }
    __syncthreads();
  }

  #pragma unroll
  for (int jt = 0; jt < 2; ++jt) {
    #pragma unroll
    for (int n = 0; n < 4; ++n) {
      f32x4 a = acc[jt][n];
      const int gk = c0 + n * 16 + lr;
      const int j0 = w * 32 + jt * 16 + lq * 4;
      float f[4];
      #pragma unroll
      for (int q = 0; q < 4; ++q) {
        const int j = j0 + q;
        f[q] = (j > gk) ? a[q] : ((j == gk) ? 0.5f * a[q] : 0.f);
      }
      u32x2 pk; pk[0] = cvt2(f[0], f[1]); pk[1] = cvt2(f[2], f[3]);
      *(u32x2*)(sB0 + swzL(n * 16 + lr, j0)) = pk;
    }
  }
  __syncthreads();

  #pragma unroll
  for (int m = 0; m < 2; ++m)
    #pragma unroll
    for (int n = 0; n < 4; ++n) acc[m][n] = (f32x4)0.f;

  for (int kb = 0; kb < 16; ++kb) {
    const int kbase = kb * 32 + lq * 8;
    bf8 bp[4];
    #pragma unroll
    for (int n = 0; n < 4; ++n)
      bp[n] = *(const bf8*)(sB0 + swzL(n * 16 + lr, kbase));
    #pragma unroll
    for (int m = 0; m < 2; ++m) {
      const float* p = Lb + (size_t)(w * 32 + m * 16 + lr) * NV + kbase;
      fv4 a0 = *(const fv4*)p;
      fv4 a1 = *(const fv4*)(p + 4);
      bf8 af = pack8(a0, a1);
      #pragma unroll
      for (int n = 0; n < 4; ++n)
        acc[m][n] = __builtin_amdgcn_mfma_f32_16x16x32_bf16(af, bp[n], acc[m][n], 0, 0, 0);
    }
  }
  #pragma unroll
  for (int m = 0; m < 2; ++m) {
    const int i0 = w * 32 + m * 16 + lq * 4;
    #pragma unroll
    for (int n = 0; n < 4; ++n) {
      f32x4 a = acc[m][n];
      const int col = c0 + n * 16 + lr;
      #pragma unroll
      for (int q = 0; q < 4; ++q)
        Ob[(size_t)(i0 + q) * NV + col] = -a[q];
    }
  }
}

extern "C" void kernel_launch(void* const* d_in, const int* in_sizes, int n_in,
                              void* d_out, int out_size, void* d_ws, size_t ws_size,
                              hipStream_t stream) {
  const float* muTE  = (const float*)d_in[0];
  const float* covTE = (const float*)d_in[1];
  const float* chol  = (const float*)d_in[2];
  float* out = (float*)d_out;

  (void)hipMemcpyAsync(out, muTE, (size_t)NB * NV * sizeof(float),
                       hipMemcpyDeviceToDevice, stream);

  float* cholTE = out + (size_t)NB * NV;
  const size_t lt_bytes = (size_t)NB * NV * NV * sizeof(unsigned short); // 64 MB

  if (ws_size >= lt_bytes) {
    unsigned short* LT = (unsigned short*)d_ws;
    convert_LT_kernel<<<dim3(NB * 64), dim3(256), 0, stream>>>(chol, LT);
    fused_cholTE_fast<<<dim3(NB * (NV / NC)), dim3(1024), 0, stream>>>(
        covTE, chol, LT, cholTE);
  } else {
    fused_cholTE_fallback<<<dim3(NB * (NV / NC)), dim3(1024), 0, stream>>>(
        covTE, chol, cholTE);
  }
}

// Round 8
// 375.894 us; speedup vs baseline: 1.6483x; 1.2775x over previous
//
#include <hip/hip_runtime.h>
#include <hip/hip_bf16.h>

#define NV 512
#define NB 128
#define NC 64

typedef float fv4 __attribute__((ext_vector_type(4)));
typedef float fv2 __attribute__((ext_vector_type(2)));
typedef float f32x4 __attribute__((ext_vector_type(4)));
typedef short bf8 __attribute__((ext_vector_type(8)));            // 8 bf16 (MFMA A/B frag)
typedef unsigned short u16x4 __attribute__((ext_vector_type(4)));
typedef unsigned short u16x8 __attribute__((ext_vector_type(8)));
typedef unsigned u32x2 __attribute__((ext_vector_type(2)));
typedef unsigned u32x4 __attribute__((ext_vector_type(4)));

// f32 -> bf16 RNE, scalar
__device__ __forceinline__ unsigned short f2bf(float f) {
  unsigned u = __builtin_bit_cast(unsigned, f);
  u += 0x7fffu + ((u >> 16) & 1u);
  return (unsigned short)(u >> 16);
}

// packed f32x2 -> bf16x2 (v_cvt_pk_bf16_f32)
__device__ __forceinline__ unsigned cvt2(float lo, float hi) {
  __hip_bfloat162 h = __float22bfloat162_rn(make_float2(lo, hi));
  unsigned r;
  __builtin_memcpy(&r, &h, sizeof(r));
  return r;
}

__device__ __forceinline__ bf8 pack8(fv4 a0, fv4 a1) {
  u32x4 r;
  r[0] = cvt2(a0[0], a0[1]);
  r[1] = cvt2(a0[2], a0[3]);
  r[2] = cvt2(a1[0], a1[1]);
  r[3] = cvt2(a1[2], a1[3]);
  return __builtin_bit_cast(bf8, r);
}

// panel: [64 cols][512 rows] bf16, 1KB per col; XOR swizzle on 16B granules
__device__ __forceinline__ int swzL(int c, int r) {
  return ((c << 10) + (r << 1)) ^ ((c & 7) << 4);
}
// fallback staging layout
__device__ __forceinline__ int swzC(int j, int ii) {
  return ((j << 6) + (ii << 1)) ^ ((j & 3) << 4);
}

__device__ __forceinline__ void gload_lds16(const void* g, void* l) {
  __builtin_amdgcn_global_load_lds(
      (const __attribute__((address_space(1))) unsigned int*)g,
      (__attribute__((address_space(3))) unsigned int*)l, 16, 0, 0);
}

// ---------------------------------------------------------------------------
// Convert kernels
// ---------------------------------------------------------------------------
// cov f32 -> CV bf16, straight elementwise (8 elems/thread)
__global__ __launch_bounds__(256, 4)
void conv_f32_bf16_kernel(const float* __restrict__ src, unsigned short* __restrict__ dst) {
  const size_t i8 = ((size_t)blockIdx.x * 256 + threadIdx.x) * 8;
  fv4 a0 = *(const fv4*)(src + i8);
  fv4 a1 = *(const fv4*)(src + i8 + 4);
  u32x4 r;
  r[0] = cvt2(a0[0], a0[1]); r[1] = cvt2(a0[2], a0[3]);
  r[2] = cvt2(a1[0], a1[1]); r[3] = cvt2(a1[2], a1[3]);
  *(u32x4*)(dst + i8) = r;
}

// chol f32 -> LR bf16 (row-major, optional) + LT bf16 (transposed)
__global__ __launch_bounds__(256, 4)
void convert_LT_kernel(const float* __restrict__ chol,
                       unsigned short* __restrict__ LT,
                       unsigned short* __restrict__ LR) {
  __shared__ unsigned short T[64][72];
  const int bid = blockIdx.x;
  const int b  = bid >> 6;
  const int t  = bid & 63;
  const int ti = t >> 3, tj = t & 7;

  const float* src = chol + ((size_t)b * NV + ti * 64) * NV + tj * 64;
  {
    const int r0 = threadIdx.x >> 4;
    const int c4 = (threadIdx.x & 15) * 4;
    #pragma unroll
    for (int p = 0; p < 4; ++p) {
      const int r = p * 16 + r0;
      fv4 v = *(const fv4*)(src + (size_t)r * NV + c4);
      T[c4 + 0][r] = f2bf(v[0]);
      T[c4 + 1][r] = f2bf(v[1]);
      T[c4 + 2][r] = f2bf(v[2]);
      T[c4 + 3][r] = f2bf(v[3]);
      if (LR) {
        u32x2 pk; pk[0] = cvt2(v[0], v[1]); pk[1] = cvt2(v[2], v[3]);
        *(u32x2*)(LR + ((size_t)b * NV + ti * 64 + r) * NV + tj * 64 + c4) = pk;
      }
    }
  }
  __syncthreads();
  unsigned short* dst = LT + ((size_t)b * NV + tj * 64) * NV + ti * 64;
  const int c  = threadIdx.x >> 2;
  const int k8 = (threadIdx.x & 3) * 16;
  u16x8 o0, o1;
  #pragma unroll
  for (int q = 0; q < 8; ++q) { o0[q] = T[c][k8 + q]; o1[q] = T[c][k8 + 8 + q]; }
  *(u16x8*)(dst + (size_t)c * NV + k8)     = o0;
  *(u16x8*)(dst + (size_t)c * NV + k8 + 8) = o1;
}

// ---------------------------------------------------------------------------
// v3 main kernel: all-bf16 operands, global_load_lds double-buffered A-stream,
// counted vmcnt, resident B panel, LDS ping-pong for T1/phi.
// ---------------------------------------------------------------------------

// stage A-tile K-slice t (32 k) of P[512][512] bf16 into buf[512 rows][32 k]
// (row-major, 64B/row) with read-side swizzle kq' = kq ^ ((row>>1)&3),
// applied on the SOURCE address (rule #21; gload dest is linear).
__device__ __forceinline__ void stageA(const unsigned short* P, int t, char* buf,
                                       int w, int lane) {
  #pragma unroll
  for (int cc = 0; cc < 2; ++cc) {
    const int pi  = w * 2 + cc;            // 1KB chunk = 16 rows
    const int row = pi * 16 + (lane >> 2);
    const int kq  = lane & 3;
    const unsigned short* src = P + row * NV + t * 32 + ((kq ^ ((row >> 1) & 3)) * 8);
    gload_lds16(src, buf + pi * 1024);
  }
}

template<int WN, bool STG>
__device__ __forceinline__ void gemm_step(const unsigned short* P, const char* panel,
                                          char* buf, int t, f32x4 (&acc)[2][4],
                                          int w, int lane, int lr, int lq) {
  if constexpr (WN == 2) asm volatile("s_waitcnt vmcnt(2)" ::: "memory");
  else                   asm volatile("s_waitcnt vmcnt(0)" ::: "memory");
  __syncthreads();                       // this K-slice staged by all waves
  const int kbase = t * 32 + lq * 8;
  bf8 bfr[4];
  #pragma unroll
  for (int n = 0; n < 4; ++n)
    bfr[n] = *(const bf8*)(panel + swzL(n * 16 + lr, kbase));
  bf8 af[2];
  #pragma unroll
  for (int m = 0; m < 2; ++m) {
    const int row = w * 32 + m * 16 + lr;
    af[m] = *(const bf8*)(buf + row * 64 + ((lq ^ ((row >> 1) & 3)) << 4));
  }
  __syncthreads();                       // all waves done reading buf
  if constexpr (STG) stageA(P, t + 2, buf, w, lane);   // overwrite; flies under MFMA
  #pragma unroll
  for (int m = 0; m < 2; ++m)
    #pragma unroll
    for (int n = 0; n < 4; ++n)
      acc[m][n] = __builtin_amdgcn_mfma_f32_16x16x32_bf16(af[m], bfr[n], acc[m][n], 0, 0, 0);
}

// one 512x64 = A[512x512]x(panel 512x64) GEMM phase, K-pipelined depth 2
__device__ __forceinline__ void run_phase(const unsigned short* P, const char* panel,
                                          char* bufX, char* bufY, f32x4 (&acc)[2][4],
                                          int w, int lane, int lr, int lq) {
  stageA(P, 0, bufX, w, lane);
  stageA(P, 1, bufY, w, lane);
  for (int t2 = 0; t2 < 7; ++t2) {
    gemm_step<2, true>(P, panel, bufX, 2 * t2,     acc, w, lane, lr, lq);
    gemm_step<2, true>(P, panel, bufY, 2 * t2 + 1, acc, w, lane, lr, lq);
  }
  gemm_step<2, false>(P, panel, bufX, 14, acc, w, lane, lr, lq);
  gemm_step<0, false>(P, panel, bufY, 15, acc, w, lane, lr, lq);
}

__global__ __launch_bounds__(1024, 1)
void fused_cholTE_v3(const unsigned short* __restrict__ CV,
                     const unsigned short* __restrict__ LR,
                     const unsigned short* __restrict__ LT,
                     float* __restrict__ out) {
  __shared__ __align__(16) char lds[131072];
  char* H0 = lds;            // phase B panel (cholC) -> phase C dbuf -> phase D panel (phi)
  char* H1 = lds + 65536;    // phase B dbuf -> phase C panel (T1) -> phase D dbuf

  const int tid  = threadIdx.x;
  const int w    = tid >> 6;
  const int lane = tid & 63;
  const int lr   = lane & 15;
  const int lq   = lane >> 4;

  const int bid = blockIdx.x;
  const int xcd = bid & 7;
  const int s   = bid >> 3;
  const int b   = xcd * 16 + (s >> 3);
  const int c0  = (s & 7) * NC;

  const unsigned short* CVb = CV + (size_t)b * NV * NV;
  const unsigned short* LRb = LR + (size_t)b * NV * NV;
  const unsigned short* LTb = LT + (size_t)b * NV * NV;
  float*                Ob  = out + (size_t)b * NV * NV;

  f32x4 acc[2][4];

  // ---- panel for phase B: cholC = LT rows c0..c0+63 -> H0 (source-swizzled)
  #pragma unroll
  for (int cc = 0; cc < 4; ++cc) {
    const int c = cc * 16 + w;
    const unsigned short* src = LTb + (size_t)(c0 + c) * NV + ((lane ^ (c & 7)) * 8);
    gload_lds16(src, H0 + c * 1024);
  }

  // ---- Phase B: T1 = CV @ cholC
  #pragma unroll
  for (int m = 0; m < 2; ++m)
    #pragma unroll
    for (int n = 0; n < 4; ++n) acc[m][n] = (f32x4)0.f;
  run_phase(CVb, H0, H1, H1 + 32768, acc, w, lane, lr, lq);

  // T1 -> H1 (panel format)
  #pragma unroll
  for (int m = 0; m < 2; ++m) {
    #pragma unroll
    for (int n = 0; n < 4; ++n) {
      f32x4 a = acc[m][n];
      u32x2 pk; pk[0] = cvt2(a[0], a[1]); pk[1] = cvt2(a[2], a[3]);
      *(u32x2*)(H1 + swzL(n * 16 + lr, w * 32 + m * 16 + lq * 4)) = pk;
    }
  }
  __syncthreads();

  // ---- Phase C: phi = LT-rows @ T1 (masked)
  #pragma unroll
  for (int m = 0; m < 2; ++m)
    #pragma unroll
    for (int n = 0; n < 4; ++n) acc[m][n] = (f32x4)0.f;
  run_phase(LTb, H1, H0, H0 + 32768, acc, w, lane, lr, lq);

  // mask (strict lower=1, diag=0.5, upper=0); phi -> H0 (panel format)
  #pragma unroll
  for (int jt = 0; jt < 2; ++jt) {
    #pragma unroll
    for (int n = 0; n < 4; ++n) {
      f32x4 a = acc[jt][n];
      const int gk = c0 + n * 16 + lr;
      const int j0 = w * 32 + jt * 16 + lq * 4;
      float f[4];
      #pragma unroll
      for (int q = 0; q < 4; ++q) {
        const int j = j0 + q;
        f[q] = (j > gk) ? a[q] : ((j == gk) ? 0.5f * a[q] : 0.f);
      }
      u32x2 pk; pk[0] = cvt2(f[0], f[1]); pk[1] = cvt2(f[2], f[3]);
      *(u32x2*)(H0 + swzL(n * 16 + lr, j0)) = pk;
    }
  }
  __syncthreads();

  // ---- Phase D: out = -LR @ phi
  #pragma unroll
  for (int m = 0; m < 2; ++m)
    #pragma unroll
    for (int n = 0; n < 4; ++n) acc[m][n] = (f32x4)0.f;
  run_phase(LRb, H0, H1, H1 + 32768, acc, w, lane, lr, lq);

  #pragma unroll
  for (int m = 0; m < 2; ++m) {
    const int i0 = w * 32 + m * 16 + lq * 4;
    #pragma unroll
    for (int n = 0; n < 4; ++n) {
      f32x4 a = acc[m][n];
      const int col = c0 + n * 16 + lr;
      #pragma unroll
      for (int q = 0; q < 4; ++q)
        Ob[(size_t)(i0 + q) * NV + col] = -a[q];
    }
  }
}

// ---------------------------------------------------------------------------
// LT-only fast path (R2/R4 form, ~350us) for 64MB <= ws < 192MB
// ---------------------------------------------------------------------------
__global__ __launch_bounds__(1024, 1)
void fused_cholTE_fast(const float* __restrict__ covTE,
                       const float* __restrict__ chol,
                       const unsigned short* __restrict__ LT,
                       float* __restrict__ out) {
  __shared__ __align__(16) char lds[131072];
  char* sB0 = lds;
  char* sB1 = lds + 65536;

  const int tid  = threadIdx.x;
  const int w    = tid >> 6;
  const int lane = tid & 63;
  const int lr   = lane & 15;
  const int lq   = lane >> 4;

  const int bid = blockIdx.x;
  const int xcd = bid & 7;
  const int s   = bid >> 3;
  const int b   = xcd * 16 + (s >> 3);
  const int c0  = (s & 7) * NC;

  const float*          Cb  = covTE + (size_t)b * NV * NV;
  const float*          Lb  = chol  + (size_t)b * NV * NV;
  const unsigned short* LTb = LT    + (size_t)b * NV * NV;
  float*                Ob  = out   + (size_t)b * NV * NV;

  #pragma unroll
  for (int cc = 0; cc < 4; ++cc) {
    const int c = cc * 16 + w;
    const unsigned short* src = LTb + (size_t)(c0 + c) * NV + ((lane ^ (c & 7)) * 8);
    gload_lds16(src, sB0 + c * 1024);
  }
  __syncthreads();

  f32x4 acc[2][4];
  #pragma unroll
  for (int m = 0; m < 2; ++m)
    #pragma unroll
    for (int n = 0; n < 4; ++n) acc[m][n] = (f32x4)0.f;

  for (int kb = 0; kb < 16; ++kb) {
    const int kbase = kb * 32 + lq * 8;
    bf8 bfr[4];
    #pragma unroll
    for (int n = 0; n < 4; ++n)
      bfr[n] = *(const bf8*)(sB0 + swzL(n * 16 + lr, kbase));
    #pragma unroll
    for (int m = 0; m < 2; ++m) {
      const float* p = Cb + (size_t)(w * 32 + m * 16 + lr) * NV + kbase;
      fv4 a0 = *(const fv4*)p;
      fv4 a1 = *(const fv4*)(p + 4);
      bf8 af = pack8(a0, a1);
      #pragma unroll
      for (int n = 0; n < 4; ++n)
        acc[m][n] = __builtin_amdgcn_mfma_f32_16x16x32_bf16(af, bfr[n], acc[m][n], 0, 0, 0);
    }
  }
  #pragma unroll
  for (int m = 0; m < 2; ++m) {
    #pragma unroll
    for (int n = 0; n < 4; ++n) {
      f32x4 a = acc[m][n];
      u32x2 pk; pk[0] = cvt2(a[0], a[1]); pk[1] = cvt2(a[2], a[3]);
      *(u32x2*)(sB1 + swzL(n * 16 + lr, w * 32 + m * 16 + lq * 4)) = pk;
    }
  }
  __syncthreads();

  #pragma unroll
  for (int m = 0; m < 2; ++m)
    #pragma unroll
    for (int n = 0; n < 4; ++n) acc[m][n] = (f32x4)0.f;

  for (int ib = 0; ib < 16; ++ib) {
    const int kbase = ib * 32 + lq * 8;
    bf8 bt[4];
    #pragma unroll
    for (int n = 0; n < 4; ++n)
      bt[n] = *(const bf8*)(sB1 + swzL(n * 16 + lr, kbase));
    #pragma unroll
    for (int jt = 0; jt < 2; ++jt) {
      bf8 af = *(const bf8*)(LTb + (size_t)(w * 32 + jt * 16 + lr) * NV + kbase);
      #pragma unroll
      for (int n = 0; n < 4; ++n)
        acc[jt][n] = __builtin_amdgcn_mfma_f32_16x16x32_bf16(af, bt[n], acc[jt][n], 0, 0, 0);
    }
  }
  #pragma unroll
  for (int jt = 0; jt < 2; ++jt) {
    #pragma unroll
    for (int n = 0; n < 4; ++n) {
      f32x4 a = acc[jt][n];
      const int gk = c0 + n * 16 + lr;
      const int j0 = w * 32 + jt * 16 + lq * 4;
      float f[4];
      #pragma unroll
      for (int q = 0; q < 4; ++q) {
        const int j = j0 + q;
        f[q] = (j > gk) ? a[q] : ((j == gk) ? 0.5f * a[q] : 0.f);
      }
      u32x2 pk; pk[0] = cvt2(f[0], f[1]); pk[1] = cvt2(f[2], f[3]);
      *(u32x2*)(sB0 + swzL(n * 16 + lr, j0)) = pk;
    }
  }
  __syncthreads();

  #pragma unroll
  for (int m = 0; m < 2; ++m)
    #pragma unroll
    for (int n = 0; n < 4; ++n) acc[m][n] = (f32x4)0.f;

  for (int kb = 0; kb < 16; ++kb) {
    const int kbase = kb * 32 + lq * 8;
    bf8 bp[4];
    #pragma unroll
    for (int n = 0; n < 4; ++n)
      bp[n] = *(const bf8*)(sB0 + swzL(n * 16 + lr, kbase));
    #pragma unroll
    for (int m = 0; m < 2; ++m) {
      const float* p = Lb + (size_t)(w * 32 + m * 16 + lr) * NV + kbase;
      fv4 a0 = *(const fv4*)p;
      fv4 a1 = *(const fv4*)(p + 4);
      bf8 af = pack8(a0, a1);
      #pragma unroll
      for (int n = 0; n < 4; ++n)
        acc[m][n] = __builtin_amdgcn_mfma_f32_16x16x32_bf16(af, bp[n], acc[m][n], 0, 0, 0);
    }
  }
  #pragma unroll
  for (int m = 0; m < 2; ++m) {
    const int i0 = w * 32 + m * 16 + lq * 4;
    #pragma unroll
    for (int n = 0; n < 4; ++n) {
      f32x4 a = acc[m][n];
      const int col = c0 + n * 16 + lr;
      #pragma unroll
      for (int q = 0; q < 4; ++q)
        Ob[(size_t)(i0 + q) * NV + col] = -a[q];
    }
  }
}

// ---------------------------------------------------------------------------
// No-workspace fallback (R1 form)
// ---------------------------------------------------------------------------
__global__ __launch_bounds__(1024, 1)
void fused_cholTE_fallback(const float* __restrict__ covTE,
                           const float* __restrict__ chol,
                           float* __restrict__ out) {
  __shared__ __align__(16) char lds[131072];
  char* sB0 = lds;
  char* sB1 = lds + 65536;
  char* sCh = lds;

  const int tid  = threadIdx.x;
  const int w    = tid >> 6;
  const int lane = tid & 63;
  const int lr   = lane & 15;
  const int lq   = lane >> 4;

  const int bid = blockIdx.x;
  const int xcd = bid & 7;
  const int s   = bid >> 3;
  const int b   = xcd * 16 + (s >> 3);
  const int c0  = (s & 7) * NC;

  const float* Cb = covTE + (size_t)b * NV * NV;
  const float* Lb = chol  + (size_t)b * NV * NV;
  float*       Ob = out   + (size_t)b * NV * NV;

  {
    const int rr = tid >> 4;
    const int cc = (tid & 15) * 4;
    #pragma unroll
    for (int p = 0; p < 8; ++p) {
      const int r = p * 64 + rr;
      fv4 v = *(const fv4*)(Lb + (size_t)r * NV + c0 + cc);
      *(unsigned short*)(sB0 + swzL(cc + 0, r)) = f2bf(v[0]);
      *(unsigned short*)(sB0 + swzL(cc + 1, r)) = f2bf(v[1]);
      *(unsigned short*)(sB0 + swzL(cc + 2, r)) = f2bf(v[2]);
      *(unsigned short*)(sB0 + swzL(cc + 3, r)) = f2bf(v[3]);
    }
  }
  __syncthreads();

  f32x4 acc[2][4];
  #pragma unroll
  for (int m = 0; m < 2; ++m)
    #pragma unroll
    for (int n = 0; n < 4; ++n) acc[m][n] = (f32x4)0.f;

  for (int kb = 0; kb < 16; ++kb) {
    const int kbase = kb * 32 + lq * 8;
    bf8 bfr[4];
    #pragma unroll
    for (int n = 0; n < 4; ++n)
      bfr[n] = *(const bf8*)(sB0 + swzL(n * 16 + lr, kbase));
    #pragma unroll
    for (int m = 0; m < 2; ++m) {
      const float* p = Cb + (size_t)(w * 32 + m * 16 + lr) * NV + kbase;
      fv4 a0 = *(const fv4*)p;
      fv4 a1 = *(const fv4*)(p + 4);
      bf8 af = pack8(a0, a1);
      #pragma unroll
      for (int n = 0; n < 4; ++n)
        acc[m][n] = __builtin_amdgcn_mfma_f32_16x16x32_bf16(af, bfr[n], acc[m][n], 0, 0, 0);
    }
  }
  #pragma unroll
  for (int m = 0; m < 2; ++m) {
    #pragma unroll
    for (int n = 0; n < 4; ++n) {
      f32x4 a = acc[m][n];
      u32x2 pk; pk[0] = cvt2(a[0], a[1]); pk[1] = cvt2(a[2], a[3]);
      *(u32x2*)(sB1 + swzL(n * 16 + lr, w * 32 + m * 16 + lq * 4)) = pk;
    }
  }
  __syncthreads();

  #pragma unroll
  for (int m = 0; m < 2; ++m)
    #pragma unroll
    for (int n = 0; n < 4; ++n) acc[m][n] = (f32x4)0.f;

  const int sj = (tid & 255) * 2;
  const int so = tid >> 8;

  fv2 raw[8];
  {
    const float* src = Lb + (size_t)(so * 8) * NV + sj;
    #pragma unroll
    for (int r = 0; r < 8; ++r) raw[r] = *(const fv2*)(src + (size_t)r * NV);
    u16x8 p0, p1;
    #pragma unroll
    for (int r = 0; r < 8; ++r) { p0[r] = f2bf(raw[r][0]); p1[r] = f2bf(raw[r][1]); }
    *(u16x8*)(sCh + swzC(sj + 0, so * 8)) = p0;
    *(u16x8*)(sCh + swzC(sj + 1, so * 8)) = p1;
  }
  __syncthreads();

  for (int ib = 0; ib < 16; ++ib) {
    if (ib + 1 < 16) {
      const float* src = Lb + (size_t)((ib + 1) * 32 + so * 8) * NV + sj;
      #pragma unroll
      for (int r = 0; r < 8; ++r) raw[r] = *(const fv2*)(src + (size_t)r * NV);
    }
    bf8 bt[4];
    #pragma unroll
    for (int n = 0; n < 4; ++n)
      bt[n] = *(const bf8*)(sB1 + swzL(n * 16 + lr, ib * 32 + lq * 8));
    #pragma unroll
    for (int jt = 0; jt < 2; ++jt) {
      bf8 af = *(const bf8*)(sCh + swzC(w * 32 + jt * 16 + lr, lq * 8));
      #pragma unroll
      for (int n = 0; n < 4; ++n)
        acc[jt][n] = __builtin_amdgcn_mfma_f32_16x16x32_bf16(af, bt[n], acc[jt][n], 0, 0, 0);
    }
    __syncthreads();
    if (ib + 1 < 16) {
      u16x8 p0, p1;
      #pragma unroll
      for (int r = 0; r < 8; ++r) { p0[r] = f2bf(raw[r][0]); p1[r] = f2bf(raw[r][1]); }
      *(u16x8*)(sCh + swzC(sj + 0, so * 8)) = p0;
      *(u16x8*)(sCh + swzC(sj + 1, so * 8)) = p1;
    }
    __syncthreads();
  }

  #pragma unroll
  for (int jt = 0; jt < 2; ++jt) {
    #pragma unroll
    for (int n = 0; n < 4; ++n) {
      f32x4 a = acc[jt][n];
      const int gk = c0 + n * 16 + lr;
      const int j0 = w * 32 + jt * 16 + lq * 4;
      float f[4];
      #pragma unroll
      for (int q = 0; q < 4; ++q) {
        const int j = j0 + q;
        f[q] = (j > gk) ? a[q] : ((j == gk) ? 0.5f * a[q] : 0.f);
      }
      u32x2 pk; pk[0] = cvt2(f[0], f[1]); pk[1] = cvt2(f[2], f[3]);
      *(u32x2*)(sB0 + swzL(n * 16 + lr, j0)) = pk;
    }
  }
  __syncthreads();

  #pragma unroll
  for (int m = 0; m < 2; ++m)
    #pragma unroll
    for (int n = 0; n < 4; ++n) acc[m][n] = (f32x4)0.f;

  for (int kb = 0; kb < 16; ++kb) {
    const int kbase = kb * 32 + lq * 8;
    bf8 bp[4];
    #pragma unroll
    for (int n = 0; n < 4; ++n)
      bp[n] = *(const bf8*)(sB0 + swzL(n * 16 + lr, kbase));
    #pragma unroll
    for (int m = 0; m < 2; ++m) {
      const float* p = Lb + (size_t)(w * 32 + m * 16 + lr) * NV + kbase;
      fv4 a0 = *(const fv4*)p;
      fv4 a1 = *(const fv4*)(p + 4);
      bf8 af = pack8(a0, a1);
      #pragma unroll
      for (int n = 0; n < 4; ++n)
        acc[m][n] = __builtin_amdgcn_mfma_f32_16x16x32_bf16(af, bp[n], acc[m][n], 0, 0, 0);
    }
  }
  #pragma unroll
  for (int m = 0; m < 2; ++m) {
    const int i0 = w * 32 + m * 16 + lq * 4;
    #pragma unroll
    for (int n = 0; n < 4; ++n) {
      f32x4 a = acc[m][n];
      const int col = c0 + n * 16 + lr;
      #pragma unroll
      for (int q = 0; q < 4; ++q)
        Ob[(size_t)(i0 + q) * NV + col] = -a[q];
    }
  }
}

extern "C" void kernel_launch(void* const* d_in, const int* in_sizes, int n_in,
                              void* d_out, int out_size, void* d_ws, size_t ws_size,
                              hipStream_t stream) {
  const float* muTE  = (const float*)d_in[0];
  const float* covTE = (const float*)d_in[1];
  const float* chol  = (const float*)d_in[2];
  float* out = (float*)d_out;

  (void)hipMemcpyAsync(out, muTE, (size_t)NB * NV * sizeof(float),
                       hipMemcpyDeviceToDevice, stream);

  float* cholTE = out + (size_t)NB * NV;
  const size_t nmat     = (size_t)NB * NV * NV;          // 33,554,432 elems
  const size_t lt_bytes = nmat * sizeof(unsigned short); // 64 MiB

  if (ws_size >= 3 * lt_bytes) {
    unsigned short* CV = (unsigned short*)d_ws;
    unsigned short* LR = CV + nmat;
    unsigned short* LT = LR + nmat;
    conv_f32_bf16_kernel<<<dim3(nmat / (256 * 8)), dim3(256), 0, stream>>>(covTE, CV);
    convert_LT_kernel<<<dim3(NB * 64), dim3(256), 0, stream>>>(chol, LT, LR);
    fused_cholTE_v3<<<dim3(NB * (NV / NC)), dim3(1024), 0, stream>>>(CV, LR, LT, cholTE);
  } else if (ws_size >= lt_bytes) {
    unsigned short* LT = (unsigned short*)d_ws;
    convert_LT_kernel<<<dim3(NB * 64), dim3(256), 0, stream>>>(chol, LT, nullptr);
    fused_cholTE_fast<<<dim3(NB * (NV / NC)), dim3(1024), 0, stream>>>(
        covTE, chol, LT, cholTE);
  } else {
    fused_cholTE_fallback<<<dim3(NB * (NV / NC)), dim3(1024), 0, stream>>>(
        covTE, chol, cholTE);
  }
}

// Round 9
// 320.647 us; speedup vs baseline: 1.9323x; 1.1723x over previous
//
#include <hip/hip_runtime.h>
#include <hip/hip_bf16.h>

#define NV 512
#define NB 128
#define NC 64

typedef float fv4 __attribute__((ext_vector_type(4)));
typedef float fv2 __attribute__((ext_vector_type(2)));
typedef float f32x4 __attribute__((ext_vector_type(4)));
typedef short bf8 __attribute__((ext_vector_type(8)));            // 8 bf16 (MFMA A/B frag)
typedef unsigned short u16x4 __attribute__((ext_vector_type(4)));
typedef unsigned short u16x8 __attribute__((ext_vector_type(8)));
typedef unsigned u32x2 __attribute__((ext_vector_type(2)));
typedef unsigned u32x4 __attribute__((ext_vector_type(4)));

// f32 -> bf16 RNE, scalar
__device__ __forceinline__ unsigned short f2bf(float f) {
  unsigned u = __builtin_bit_cast(unsigned, f);
  u += 0x7fffu + ((u >> 16) & 1u);
  return (unsigned short)(u >> 16);
}

// packed f32x2 -> bf16x2 (v_cvt_pk_bf16_f32)
__device__ __forceinline__ unsigned cvt2(float lo, float hi) {
  __hip_bfloat162 h = __float22bfloat162_rn(make_float2(lo, hi));
  unsigned r;
  __builtin_memcpy(&r, &h, sizeof(r));
  return r;
}

__device__ __forceinline__ bf8 pack8(fv4 a0, fv4 a1) {
  u32x4 r;
  r[0] = cvt2(a0[0], a0[1]);
  r[1] = cvt2(a0[2], a0[3]);
  r[2] = cvt2(a1[0], a1[1]);
  r[3] = cvt2(a1[2], a1[3]);
  return __builtin_bit_cast(bf8, r);
}

// panel: [64 cols][512 rows] bf16, 1KB per col; XOR swizzle on 16B granules
__device__ __forceinline__ int swzL(int c, int r) {
  return ((c << 10) + (r << 1)) ^ ((c & 7) << 4);
}
// fallback staging layout
__device__ __forceinline__ int swzC(int j, int ii) {
  return ((j << 6) + (ii << 1)) ^ ((j & 3) << 4);
}

__device__ __forceinline__ void gload_lds16(const void* g, void* l) {
  __builtin_amdgcn_global_load_lds(
      (const __attribute__((address_space(1))) unsigned int*)g,
      (__attribute__((address_space(3))) unsigned int*)l, 16, 0, 0);
}

// ---------------------------------------------------------------------------
// Convert kernels
// ---------------------------------------------------------------------------
__global__ __launch_bounds__(256, 4)
void conv_f32_bf16_kernel(const float* __restrict__ src, unsigned short* __restrict__ dst) {
  const size_t i8 = ((size_t)blockIdx.x * 256 + threadIdx.x) * 8;
  fv4 a0 = *(const fv4*)(src + i8);
  fv4 a1 = *(const fv4*)(src + i8 + 4);
  u32x4 r;
  r[0] = cvt2(a0[0], a0[1]); r[1] = cvt2(a0[2], a0[3]);
  r[2] = cvt2(a1[0], a1[1]); r[3] = cvt2(a1[2], a1[3]);
  *(u32x4*)(dst + i8) = r;
}

// chol f32 -> LR bf16 (row-major, optional) + LT bf16 (transposed)
__global__ __launch_bounds__(256, 4)
void convert_LT_kernel(const float* __restrict__ chol,
                       unsigned short* __restrict__ LT,
                       unsigned short* __restrict__ LR) {
  __shared__ unsigned short T[64][72];
  const int bid = blockIdx.x;
  const int b  = bid >> 6;
  const int t  = bid & 63;
  const int ti = t >> 3, tj = t & 7;

  const float* src = chol + ((size_t)b * NV + ti * 64) * NV + tj * 64;
  {
    const int r0 = threadIdx.x >> 4;
    const int c4 = (threadIdx.x & 15) * 4;
    #pragma unroll
    for (int p = 0; p < 4; ++p) {
      const int r = p * 16 + r0;
      fv4 v = *(const fv4*)(src + (size_t)r * NV + c4);
      T[c4 + 0][r] = f2bf(v[0]);
      T[c4 + 1][r] = f2bf(v[1]);
      T[c4 + 2][r] = f2bf(v[2]);
      T[c4 + 3][r] = f2bf(v[3]);
      if (LR) {
        u32x2 pk; pk[0] = cvt2(v[0], v[1]); pk[1] = cvt2(v[2], v[3]);
        *(u32x2*)(LR + ((size_t)b * NV + ti * 64 + r) * NV + tj * 64 + c4) = pk;
      }
    }
  }
  __syncthreads();
  unsigned short* dst = LT + ((size_t)b * NV + tj * 64) * NV + ti * 64;
  const int c  = threadIdx.x >> 2;
  const int k8 = (threadIdx.x & 3) * 16;
  u16x8 o0, o1;
  #pragma unroll
  for (int q = 0; q < 8; ++q) { o0[q] = T[c][k8 + q]; o1[q] = T[c][k8 + 8 + q]; }
  *(u16x8*)(dst + (size_t)c * NV + k8)     = o0;
  *(u16x8*)(dst + (size_t)c * NV + k8 + 8) = o1;
}

// ---------------------------------------------------------------------------
// v4 main kernel: all-bf16 operands; B-panel resident in LDS; A-fragments
// read DIRECTLY from global (K-contiguous bf16, L2-served). Zero barriers
// inside the K-loops — waves free-run, compiler pipelines the loads.
// ---------------------------------------------------------------------------
__device__ __forceinline__ void phase_direct(const unsigned short* Abase,
                                             const char* panel,
                                             f32x4 (&acc)[2][4],
                                             int w, int lr, int lq) {
  const unsigned short* rA0 = Abase + (size_t)(w * 32 + lr) * NV + lq * 8;
  const unsigned short* rA1 = rA0 + 16 * NV;
  #pragma unroll 4
  for (int t = 0; t < 16; ++t) {
    const int kbase = t * 32 + lq * 8;
    bf8 a0 = *(const bf8*)(rA0 + t * 32);
    bf8 a1 = *(const bf8*)(rA1 + t * 32);
    bf8 bfr[4];
    #pragma unroll
    for (int n = 0; n < 4; ++n)
      bfr[n] = *(const bf8*)(panel + swzL(n * 16 + lr, kbase));
    #pragma unroll
    for (int n = 0; n < 4; ++n)
      acc[0][n] = __builtin_amdgcn_mfma_f32_16x16x32_bf16(a0, bfr[n], acc[0][n], 0, 0, 0);
    #pragma unroll
    for (int n = 0; n < 4; ++n)
      acc[1][n] = __builtin_amdgcn_mfma_f32_16x16x32_bf16(a1, bfr[n], acc[1][n], 0, 0, 0);
  }
}

__global__ __launch_bounds__(1024, 1)
void fused_cholTE_v4(const unsigned short* __restrict__ CV,
                     const unsigned short* __restrict__ LR,
                     const unsigned short* __restrict__ LT,
                     float* __restrict__ out) {
  __shared__ __align__(16) char lds[131072];
  char* H0 = lds;            // phase B panel (cholC); then phi panel (phase D)
  char* H1 = lds + 65536;    // T1 panel (phase C)

  const int tid  = threadIdx.x;
  const int w    = tid >> 6;
  const int lane = tid & 63;
  const int lr   = lane & 15;
  const int lq   = lane >> 4;

  const int bid = blockIdx.x;
  const int xcd = bid & 7;
  const int s   = bid >> 3;
  const int b   = xcd * 16 + (s >> 3);
  const int c0  = (s & 7) * NC;

  const unsigned short* CVb = CV + (size_t)b * NV * NV;
  const unsigned short* LRb = LR + (size_t)b * NV * NV;
  const unsigned short* LTb = LT + (size_t)b * NV * NV;
  float*                Ob  = out + (size_t)b * NV * NV;

  f32x4 acc[2][4];

  // ---- load phase-B panel: cholC = LT rows c0..c0+63 -> H0 (source-swizzled)
  #pragma unroll
  for (int cc = 0; cc < 4; ++cc) {
    const int c = cc * 16 + w;
    const unsigned short* src = LTb + (size_t)(c0 + c) * NV + ((lane ^ (c & 7)) * 8);
    gload_lds16(src, H0 + c * 1024);
  }
  asm volatile("s_waitcnt vmcnt(0)" ::: "memory");
  __syncthreads();   // barrier 1: panel visible to all waves

  // ---- Phase B: T1 = CV @ cholC   (A direct from global)
  #pragma unroll
  for (int m = 0; m < 2; ++m)
    #pragma unroll
    for (int n = 0; n < 4; ++n) acc[m][n] = (f32x4)0.f;
  phase_direct(CVb, H0, acc, w, lr, lq);

  // T1 -> H1 (panel format); H0 still being read by slow waves — H1 is safe.
  #pragma unroll
  for (int m = 0; m < 2; ++m) {
    #pragma unroll
    for (int n = 0; n < 4; ++n) {
      f32x4 a = acc[m][n];
      u32x2 pk; pk[0] = cvt2(a[0], a[1]); pk[1] = cvt2(a[2], a[3]);
      *(u32x2*)(H1 + swzL(n * 16 + lr, w * 32 + m * 16 + lq * 4)) = pk;
    }
  }
  __syncthreads();   // barrier 2: T1 complete; H0 now dead

  // ---- Phase C: phi = LT-rows @ T1 (masked)   (A direct from global)
  #pragma unroll
  for (int m = 0; m < 2; ++m)
    #pragma unroll
    for (int n = 0; n < 4; ++n) acc[m][n] = (f32x4)0.f;
  phase_direct(LTb, H1, acc, w, lr, lq);

  // mask (strict lower=1, diag=0.5, upper=0); phi -> H0 (dead since barrier 2)
  #pragma unroll
  for (int jt = 0; jt < 2; ++jt) {
    #pragma unroll
    for (int n = 0; n < 4; ++n) {
      f32x4 a = acc[jt][n];
      const int gk = c0 + n * 16 + lr;
      const int j0 = w * 32 + jt * 16 + lq * 4;
      float f[4];
      #pragma unroll
      for (int q = 0; q < 4; ++q) {
        const int j = j0 + q;
        f[q] = (j > gk) ? a[q] : ((j == gk) ? 0.5f * a[q] : 0.f);
      }
      u32x2 pk; pk[0] = cvt2(f[0], f[1]); pk[1] = cvt2(f[2], f[3]);
      *(u32x2*)(H0 + swzL(n * 16 + lr, j0)) = pk;
    }
  }
  __syncthreads();   // barrier 3: phi complete

  // ---- Phase D: out = -LR @ phi   (A direct from global)
  #pragma unroll
  for (int m = 0; m < 2; ++m)
    #pragma unroll
    for (int n = 0; n < 4; ++n) acc[m][n] = (f32x4)0.f;
  phase_direct(LRb, H0, acc, w, lr, lq);

  #pragma unroll
  for (int m = 0; m < 2; ++m) {
    const int i0 = w * 32 + m * 16 + lq * 4;
    #pragma unroll
    for (int n = 0; n < 4; ++n) {
      f32x4 a = acc[m][n];
      const int col = c0 + n * 16 + lr;
      #pragma unroll
      for (int q = 0; q < 4; ++q)
        Ob[(size_t)(i0 + q) * NV + col] = -a[q];
    }
  }
}

// ---------------------------------------------------------------------------
// LT-only fast path (R2 form) for 64MB <= ws < 192MB
// ---------------------------------------------------------------------------
__global__ __launch_bounds__(1024, 1)
void fused_cholTE_fast(const float* __restrict__ covTE,
                       const float* __restrict__ chol,
                       const unsigned short* __restrict__ LT,
                       float* __restrict__ out) {
  __shared__ __align__(16) char lds[131072];
  char* sB0 = lds;
  char* sB1 = lds + 65536;

  const int tid  = threadIdx.x;
  const int w    = tid >> 6;
  const int lane = tid & 63;
  const int lr   = lane & 15;
  const int lq   = lane >> 4;

  const int bid = blockIdx.x;
  const int xcd = bid & 7;
  const int s   = bid >> 3;
  const int b   = xcd * 16 + (s >> 3);
  const int c0  = (s & 7) * NC;

  const float*          Cb  = covTE + (size_t)b * NV * NV;
  const float*          Lb  = chol  + (size_t)b * NV * NV;
  const unsigned short* LTb = LT    + (size_t)b * NV * NV;
  float*                Ob  = out   + (size_t)b * NV * NV;

  #pragma unroll
  for (int cc = 0; cc < 4; ++cc) {
    const int c = cc * 16 + w;
    const unsigned short* src = LTb + (size_t)(c0 + c) * NV + ((lane ^ (c & 7)) * 8);
    gload_lds16(src, sB0 + c * 1024);
  }
  __syncthreads();

  f32x4 acc[2][4];
  #pragma unroll
  for (int m = 0; m < 2; ++m)
    #pragma unroll
    for (int n = 0; n < 4; ++n) acc[m][n] = (f32x4)0.f;

  for (int kb = 0; kb < 16; ++kb) {
    const int kbase = kb * 32 + lq * 8;
    bf8 bfr[4];
    #pragma unroll
    for (int n = 0; n < 4; ++n)
      bfr[n] = *(const bf8*)(sB0 + swzL(n * 16 + lr, kbase));
    #pragma unroll
    for (int m = 0; m < 2; ++m) {
      const float* p = Cb + (size_t)(w * 32 + m * 16 + lr) * NV + kbase;
      fv4 a0 = *(const fv4*)p;
      fv4 a1 = *(const fv4*)(p + 4);
      bf8 af = pack8(a0, a1);
      #pragma unroll
      for (int n = 0; n < 4; ++n)
        acc[m][n] = __builtin_amdgcn_mfma_f32_16x16x32_bf16(af, bfr[n], acc[m][n], 0, 0, 0);
    }
  }
  #pragma unroll
  for (int m = 0; m < 2; ++m) {
    #pragma unroll
    for (int n = 0; n < 4; ++n) {
      f32x4 a = acc[m][n];
      u32x2 pk; pk[0] = cvt2(a[0], a[1]); pk[1] = cvt2(a[2], a[3]);
      *(u32x2*)(sB1 + swzL(n * 16 + lr, w * 32 + m * 16 + lq * 4)) = pk;
    }
  }
  __syncthreads();

  #pragma unroll
  for (int m = 0; m < 2; ++m)
    #pragma unroll
    for (int n = 0; n < 4; ++n) acc[m][n] = (f32x4)0.f;

  for (int ib = 0; ib < 16; ++ib) {
    const int kbase = ib * 32 + lq * 8;
    bf8 bt[4];
    #pragma unroll
    for (int n = 0; n < 4; ++n)
      bt[n] = *(const bf8*)(sB1 + swzL(n * 16 + lr, kbase));
    #pragma unroll
    for (int jt = 0; jt < 2; ++jt) {
      bf8 af = *(const bf8*)(LTb + (size_t)(w * 32 + jt * 16 + lr) * NV + kbase);
      #pragma unroll
      for (int n = 0; n < 4; ++n)
        acc[jt][n] = __builtin_amdgcn_mfma_f32_16x16x32_bf16(af, bt[n], acc[jt][n], 0, 0, 0);
    }
  }
  #pragma unroll
  for (int jt = 0; jt < 2; ++jt) {
    #pragma unroll
    for (int n = 0; n < 4; ++n) {
      f32x4 a = acc[jt][n];
      const int gk = c0 + n * 16 + lr;
      const int j0 = w * 32 + jt * 16 + lq * 4;
      float f[4];
      #pragma unroll
      for (int q = 0; q < 4; ++q) {
        const int j = j0 + q;
        f[q] = (j > gk) ? a[q] : ((j == gk) ? 0.5f * a[q] : 0.f);
      }
      u32x2 pk; pk[0] = cvt2(f[0], f[1]); pk[1] = cvt2(f[2], f[3]);
      *(u32x2*)(sB0 + swzL(n * 16 + lr, j0)) = pk;
    }
  }
  __syncthreads();

  #pragma unroll
  for (int m = 0; m < 2; ++m)
    #pragma unroll
    for (int n = 0; n < 4; ++n) acc[m][n] = (f32x4)0.f;

  for (int kb = 0; kb < 16; ++kb) {
    const int kbase = kb * 32 + lq * 8;
    bf8 bp[4];
    #pragma unroll
    for (int n = 0; n < 4; ++n)
      bp[n] = *(const bf8*)(sB0 + swzL(n * 16 + lr, kbase));
    #pragma unroll
    for (int m = 0; m < 2; ++m) {
      const float* p = Lb + (size_t)(w * 32 + m * 16 + lr) * NV + kbase;
      fv4 a0 = *(const fv4*)p;
      fv4 a1 = *(const fv4*)(p + 4);
      bf8 af = pack8(a0, a1);
      #pragma unroll
      for (int n = 0; n < 4; ++n)
        acc[m][n] = __builtin_amdgcn_mfma_f32_16x16x32_bf16(af, bp[n], acc[m][n], 0, 0, 0);
    }
  }
  #pragma unroll
  for (int m = 0; m < 2; ++m) {
    const int i0 = w * 32 + m * 16 + lq * 4;
    #pragma unroll
    for (int n = 0; n < 4; ++n) {
      f32x4 a = acc[m][n];
      const int col = c0 + n * 16 + lr;
      #pragma unroll
      for (int q = 0; q < 4; ++q)
        Ob[(size_t)(i0 + q) * NV + col] = -a[q];
    }
  }
}

// ---------------------------------------------------------------------------
// No-workspace fallback (R1 form)
// ---------------------------------------------------------------------------
__global__ __launch_bounds__(1024, 1)
void fused_cholTE_fallback(const float* __restrict__ covTE,
                           const float* __restrict__ chol,
                           float* __restrict__ out) {
  __shared__ __align__(16) char lds[131072];
  char* sB0 = lds;
  char* sB1 = lds + 65536;
  char* sCh = lds;

  const int tid  = threadIdx.x;
  const int w    = tid >> 6;
  const int lane = tid & 63;
  const int lr   = lane & 15;
  const int lq   = lane >> 4;

  const int bid = blockIdx.x;
  const int xcd = bid & 7;
  const int s   = bid >> 3;
  const int b   = xcd * 16 + (s >> 3);
  const int c0  = (s & 7) * NC;

  const float* Cb = covTE + (size_t)b * NV * NV;
  const float* Lb = chol  + (size_t)b * NV * NV;
  float*       Ob = out   + (size_t)b * NV * NV;

  {
    const int rr = tid >> 4;
    const int cc = (tid & 15) * 4;
    #pragma unroll
    for (int p = 0; p < 8; ++p) {
      const int r = p * 64 + rr;
      fv4 v = *(const fv4*)(Lb + (size_t)r * NV + c0 + cc);
      *(unsigned short*)(sB0 + swzL(cc + 0, r)) = f2bf(v[0]);
      *(unsigned short*)(sB0 + swzL(cc + 1, r)) = f2bf(v[1]);
      *(unsigned short*)(sB0 + swzL(cc + 2, r)) = f2bf(v[2]);
      *(unsigned short*)(sB0 + swzL(cc + 3, r)) = f2bf(v[3]);
    }
  }
  __syncthreads();

  f32x4 acc[2][4];
  #pragma unroll
  for (int m = 0; m < 2; ++m)
    #pragma unroll
    for (int n = 0; n < 4; ++n) acc[m][n] = (f32x4)0.f;

  for (int kb = 0; kb < 16; ++kb) {
    const int kbase = kb * 32 + lq * 8;
    bf8 bfr[4];
    #pragma unroll
    for (int n = 0; n < 4; ++n)
      bfr[n] = *(const bf8*)(sB0 + swzL(n * 16 + lr, kbase));
    #pragma unroll
    for (int m = 0; m < 2; ++m) {
      const float* p = Cb + (size_t)(w * 32 + m * 16 + lr) * NV + kbase;
      fv4 a0 = *(const fv4*)p;
      fv4 a1 = *(const fv4*)(p + 4);
      bf8 af = pack8(a0, a1);
      #pragma unroll
      for (int n = 0; n < 4; ++n)
        acc[m][n] = __builtin_amdgcn_mfma_f32_16x16x32_bf16(af, bfr[n], acc[m][n], 0, 0, 0);
    }
  }
  #pragma unroll
  for (int m = 0; m < 2; ++m) {
    #pragma unroll
    for (int n = 0; n < 4; ++n) {
      f32x4 a = acc[m][n];
      u32x2 pk; pk[0] = cvt2(a[0], a[1]); pk[1] = cvt2(a[2], a[3]);
      *(u32x2*)(sB1 + swzL(n * 16 + lr, w * 32 + m * 16 + lq * 4)) = pk;
    }
  }
  __syncthreads();

  #pragma unroll
  for (int m = 0; m < 2; ++m)
    #pragma unroll
    for (int n = 0; n < 4; ++n) acc[m][n] = (f32x4)0.f;

  const int sj = (tid & 255) * 2;
  const int so = tid >> 8;

  fv2 raw[8];
  {
    const float* src = Lb + (size_t)(so * 8) * NV + sj;
    #pragma unroll
    for (int r = 0; r < 8; ++r) raw[r] = *(const fv2*)(src + (size_t)r * NV);
    u16x8 p0, p1;
    #pragma unroll
    for (int r = 0; r < 8; ++r) { p0[r] = f2bf(raw[r][0]); p1[r] = f2bf(raw[r][1]); }
    *(u16x8*)(sCh + swzC(sj + 0, so * 8)) = p0;
    *(u16x8*)(sCh + swzC(sj + 1, so * 8)) = p1;
  }
  __syncthreads();

  for (int ib = 0; ib < 16; ++ib) {
    if (ib + 1 < 16) {
      const float* src = Lb + (size_t)((ib + 1) * 32 + so * 8) * NV + sj;
      #pragma unroll
      for (int r = 0; r < 8; ++r) raw[r] = *(const fv2*)(src + (size_t)r * NV);
    }
    bf8 bt[4];
    #pragma unroll
    for (int n = 0; n < 4; ++n)
      bt[n] = *(const bf8*)(sB1 + swzL(n * 16 + lr, ib * 32 + lq * 8));
    #pragma unroll
    for (int jt = 0; jt < 2; ++jt) {
      bf8 af = *(const bf8*)(sCh + swzC(w * 32 + jt * 16 + lr, lq * 8));
      #pragma unroll
      for (int n = 0; n < 4; ++n)
        acc[jt][n] = __builtin_amdgcn_mfma_f32_16x16x32_bf16(af, bt[n], acc[jt][n], 0, 0, 0);
    }
    __syncthreads();
    if (ib + 1 < 16) {
      u16x8 p0, p1;
      #pragma unroll
      for (int r = 0; r < 8; ++r) { p0[r] = f2bf(raw[r][0]); p1[r] = f2bf(raw[r][1]); }
      *(u16x8*)(sCh + swzC(sj + 0, so * 8)) = p0;
      *(u16x8*)(sCh + swzC(sj + 1, so * 8)) = p1;
    }
    __syncthreads();
  }

  #pragma unroll
  for (int jt = 0; jt < 2; ++jt) {
    #pragma unroll
    for (int n = 0; n < 4; ++n) {
      f32x4 a = acc[jt][n];
      const int gk = c0 + n * 16 + lr;
      const int j0 = w * 32 + jt * 16 + lq * 4;
      float f[4];
      #pragma unroll
      for (int q = 0; q < 4; ++q) {
        const int j = j0 + q;
        f[q] = (j > gk) ? a[q] : ((j == gk) ? 0.5f * a[q] : 0.f);
      }
      u32x2 pk; pk[0] = cvt2(f[0], f[1]); pk[1] = cvt2(f[2], f[3]);
      *(u32x2*)(sB0 + swzL(n * 16 + lr, j0)) = pk;
    }
  }
  __syncthreads();

  #pragma unroll
  for (int m = 0; m < 2; ++m)
    #pragma unroll
    for (int n = 0; n < 4; ++n) acc[m][n] = (f32x4)0.f;

  for (int kb = 0; kb < 16; ++kb) {
    const int kbase = kb * 32 + lq * 8;
    bf8 bp[4];
    #pragma unroll
    for (int n = 0; n < 4; ++n)
      bp[n] = *(const bf8*)(sB0 + swzL(n * 16 + lr, kbase));
    #pragma unroll
    for (int m = 0; m < 2; ++m) {
      const float* p = Lb + (size_t)(w * 32 + m * 16 + lr) * NV + kbase;
      fv4 a0 = *(const fv4*)p;
      fv4 a1 = *(const fv4*)(p + 4);
      bf8 af = pack8(a0, a1);
      #pragma unroll
      for (int n = 0; n < 4; ++n)
        acc[m][n] = __builtin_amdgcn_mfma_f32_16x16x32_bf16(af, bp[n], acc[m][n], 0, 0, 0);
    }
  }
  #pragma unroll
  for (int m = 0; m < 2; ++m) {
    const int i0 = w * 32 + m * 16 + lq * 4;
    #pragma unroll
    for (int n = 0; n < 4; ++n) {
      f32x4 a = acc[m][n];
      const int col = c0 + n * 16 + lr;
      #pragma unroll
      for (int q = 0; q < 4; ++q)
        Ob[(size_t)(i0 + q) * NV + col] = -a[q];
    }
  }
}

extern "C" void kernel_launch(void* const* d_in, const int* in_sizes, int n_in,
                              void* d_out, int out_size, void* d_ws, size_t ws_size,
                              hipStream_t stream) {
  const float* muTE  = (const float*)d_in[0];
  const float* covTE = (const float*)d_in[1];
  const float* chol  = (const float*)d_in[2];
  float* out = (float*)d_out;

  (void)hipMemcpyAsync(out, muTE, (size_t)NB * NV * sizeof(float),
                       hipMemcpyDeviceToDevice, stream);

  float* cholTE = out + (size_t)NB * NV;
  const size_t nmat     = (size_t)NB * NV * NV;          // 33,554,432 elems
  const size_t lt_bytes = nmat * sizeof(unsigned short); // 64 MiB

  if (ws_size >= 3 * lt_bytes) {
    unsigned short* CV = (unsigned short*)d_ws;
    unsigned short* LR = CV + nmat;
    unsigned short* LT = LR + nmat;
    conv_f32_bf16_kernel<<<dim3(nmat / (256 * 8)), dim3(256), 0, stream>>>(covTE, CV);
    convert_LT_kernel<<<dim3(NB * 64), dim3(256), 0, stream>>>(chol, LT, LR);
    fused_cholTE_v4<<<dim3(NB * (NV / NC)), dim3(1024), 0, stream>>>(CV, LR, LT, cholTE);
  } else if (ws_size >= lt_bytes) {
    unsigned short* LT = (unsigned short*)d_ws;
    convert_LT_kernel<<<dim3(NB * 64), dim3(256), 0, stream>>>(chol, LT, nullptr);
    fused_cholTE_fast<<<dim3(NB * (NV / NC)), dim3(1024), 0, stream>>>(
        covTE, chol, LT, cholTE);
  } else {
    fused_cholTE_fallback<<<dim3(NB * (NV / NC)), dim3(1024), 0, stream>>>(
        covTE, chol, cholTE);
  }
}